// Round 12
// baseline (127.023 us; speedup 1.0000x reference)
//
#include <hip/hip_runtime.h>

#define NWIN 4096
#define NTOK 49
#define DIMC 128
#define QK_SCALE 0.17677669529663689f  // 32^-0.5

typedef __attribute__((ext_vector_type(8))) short vs8;        // 8 bf16 (4 VGPRs)
typedef __attribute__((ext_vector_type(4))) float vf4;
typedef __attribute__((ext_vector_type(2))) unsigned vu2;     // 2 packed bf16x2
typedef __attribute__((ext_vector_type(4))) _Float16 vh4;     // 4 f16 (2 VGPRs)
typedef __attribute__((ext_vector_type(8))) _Float16 vh8;     // 8 f16 (4 VGPRs) — K=32 MFMA operand
typedef __attribute__((ext_vector_type(2))) __fp16 vp2;       // cvt_pkrtz result type

__device__ __forceinline__ unsigned cvtpk(float a, float b) {  // 2xf32 -> packed bf16x2
  unsigned r;
  asm("v_cvt_pk_bf16_f32 %0, %1, %2" : "=v"(r) : "v"(a), "v"(b));
  return r;
}

__device__ __forceinline__ vh4 pack4h(float a0, float a1, float a2, float a3) {
  union { vh4 v; vp2 h[2]; } u;
  u.h[0] = __builtin_amdgcn_cvt_pkrtz(a0, a1);
  u.h[1] = __builtin_amdgcn_cvt_pkrtz(a2, a3);
  return u.v;
}

__device__ __forceinline__ vh8 cat8(vh4 a, vh4 b) {
  union { vh8 v8; vh4 v4[2]; } u;
  u.v4[0] = a; u.v4[1] = b;
  return u.v8;
}

__device__ __forceinline__ vf4 unpack_bf4(vu2 b) {  // 4 packed bf16 -> vf4
  union { unsigned u; float f; } a0, a1, a2, a3;
  a0.u = b[0] << 16; a1.u = b[0] & 0xffff0000u;
  a2.u = b[1] << 16; a3.u = b[1] & 0xffff0000u;
  return (vf4){a0.f, a1.f, a2.f, a3.f};
}

__device__ __forceinline__ short f2bf(float f) {
  union { float f; unsigned u; } x; x.f = f;
  unsigned r = x.u + 0x7fffu + ((x.u >> 16) & 1u);
  return (short)(r >> 16);
}

// ---------------- prep: weights->bf16, bias table -> padded bf16 [4][64][64] ----------------
__global__ void prep_kernel(const float* __restrict__ qkv_w, const float* __restrict__ proj_w,
                            const float* __restrict__ bias_table, const int* __restrict__ rel_index,
                            short* __restrict__ qkv_wb, short* __restrict__ proj_wb,
                            short* __restrict__ bias_bf) {
  int i = blockIdx.x * 256 + threadIdx.x;
  if (i < 49152) qkv_wb[i] = f2bf(qkv_w[i]);
  int j = i - 49152;
  if (j >= 0 && j < 16384) proj_wb[j] = f2bf(proj_w[j]);
  int k = i - 65536;
  if (k >= 0 && k < 16384) {
    int h = k >> 12, rc = k & 4095, r = rc >> 6, c = rc & 63;
    float v = -1e30f;
    if (r < NTOK && c < NTOK) v = bias_table[rel_index[r * NTOK + c] * 4 + h];
    bias_bf[k] = f2bf(v);
  }
}

// ---------------- fused window attention ----------------
// block = 1 window, 4 waves; wave w owns head w END-TO-END in registers.
// __launch_bounds__(256,3): the one empirically spill-free squeezed point
// (R4: exactly 84 VGPR, clean FETCH) -> 6 waves/SIMD HW cap, occ ~30%.
// (one-arg natural=124 VGPR caps HW at 4 waves/SIMD, occ 22% — R11.)
// No-max softmax (|S|<~7; exp fp32, P<=~1100 in f16), per-head normalization
// at O-write. K=32 f16 attention MFMAs. Bias as MFMA C-in.
// Staging restructured: issue x-loads -> issue Q/dt0 weight prefetch -> cvt+write
// -> barrier, so first-tile weight latency hides under staging (loads can't be
// compiler-hoisted across __syncthreads).
// LDS 16KB: X staging then O exchange. 3 barriers.
__launch_bounds__(256, 3)
__global__ void win_attn(const float* __restrict__ x,
                         const float* __restrict__ qkv_b,
                         const float* __restrict__ proj_b,
                         const short* __restrict__ qkv_wb,
                         const short* __restrict__ proj_wb,
                         const short* __restrict__ bias_bf,
                         float* __restrict__ out) {
  __shared__ __align__(16) char lds[16384];

  const int tid  = threadIdx.x;
  const int lane = tid & 63;
  const int w    = tid >> 6;
  const int l15  = lane & 15;
  const int g    = lane >> 4;
  const int win  = blockIdx.x;

  // ---- stage X: issue ALL global loads first ----
  const float* xw = x + (size_t)win * (NTOK * DIMC);
  vf4 xa[4], xb[4];
  int srow[4], sc16[4];
#pragma unroll
  for (int it = 0; it < 4; ++it) {
    int chunk = tid + it * 256;
    srow[it] = chunk >> 4; sc16[it] = chunk & 15;
    if (srow[it] < NTOK) {
      const float* src = xw + srow[it] * DIMC + sc16[it] * 8;
      xa[it] = *(const vf4*)src;
      xb[it] = *(const vf4*)(src + 4);
    }
  }

  // ---- prefetch Q/dt0 weights + bias (independent of x; hides under staging) ----
  vs8 bwQ0[4];
  vf4 qb0;
  {
    const short* wrow = qkv_wb + (2 * w * 16 + l15) * DIMC;
#pragma unroll
    for (int kk = 0; kk < 4; ++kk) bwQ0[kk] = *(const vs8*)(wrow + kk * 32 + g * 8);
    qb0 = *(const vf4*)(qkv_b + 2 * w * 16 + g * 4);
  }

  // ---- convert + write staging ----
#pragma unroll
  for (int it = 0; it < 4; ++it) {
    union { vs8 s; unsigned u[4]; } pk;
    if (srow[it] < NTOK) {
      pk.u[0] = cvtpk(xa[it].x, xa[it].y); pk.u[1] = cvtpk(xa[it].z, xa[it].w);
      pk.u[2] = cvtpk(xb[it].x, xb[it].y); pk.u[3] = cvtpk(xb[it].z, xb[it].w);
    } else {
      pk.u[0] = pk.u[1] = pk.u[2] = pk.u[3] = 0u;
    }
    *(vs8*)(lds + srow[it] * 256 + ((sc16[it] * 16) ^ ((srow[it] & 7) << 4))) = pk.s;
  }
  __syncthreads();

  // ---- X fragments, register-resident for all of GEMM1 ----
  vs8 pa[4][4];
#pragma unroll
  for (int tr = 0; tr < 4; ++tr) {
    int row = tr * 16 + l15;
#pragma unroll
    for (int kk = 0; kk < 4; ++kk)
      pa[tr][kk] = *(const vs8*)(lds + row * 256 + ((kk * 64 + g * 16) ^ ((row & 7) << 4)));
  }
  __syncthreads();  // X dead in LDS -> buffer reusable for O exchange

  // ---- GEMM1: wave w computes head w's Q, K (swapped) and V (normal) ----
  vh4 qB[2][4], kA[2][4], vA[2][4];   // [dim-tile dt][token-tile]
#pragma unroll
  for (int dt = 0; dt < 2; ++dt) {
    {  // Q: c = 2w+dt, swapped -> lane: token=tr*16+l15, dims c*16+g*4+r
      const int c = 2 * w + dt;
      vs8 bw[4];
      vf4 qb;
      if (dt == 0) {
#pragma unroll
        for (int kk = 0; kk < 4; ++kk) bw[kk] = bwQ0[kk];
        qb = qb0;
      } else {
        const short* wrow = qkv_wb + (c * 16 + l15) * DIMC;
#pragma unroll
        for (int kk = 0; kk < 4; ++kk) bw[kk] = *(const vs8*)(wrow + kk * 32 + g * 8);
        qb = *(const vf4*)(qkv_b + c * 16 + g * 4);
      }
      vf4 acc[4];
#pragma unroll
      for (int tr = 0; tr < 4; ++tr) acc[tr] = qb;
#pragma unroll
      for (int kk = 0; kk < 4; ++kk)
#pragma unroll
        for (int tr = 0; tr < 4; ++tr)
          acc[tr] = __builtin_amdgcn_mfma_f32_16x16x32_bf16(bw[kk], pa[tr][kk], acc[tr], 0, 0, 0);
#pragma unroll
      for (int tr = 0; tr < 4; ++tr)
        qB[dt][tr] = pack4h(acc[tr][0] * QK_SCALE, acc[tr][1] * QK_SCALE,
                            acc[tr][2] * QK_SCALE, acc[tr][3] * QK_SCALE);
    }
    {  // K: c = 8+2w+dt, swapped
      const int c = 8 + 2 * w + dt;
      vs8 bw[4];
      const short* wrow = qkv_wb + (c * 16 + l15) * DIMC;
#pragma unroll
      for (int kk = 0; kk < 4; ++kk) bw[kk] = *(const vs8*)(wrow + kk * 32 + g * 8);
      vf4 kb = *(const vf4*)(qkv_b + c * 16 + g * 4);
      vf4 acc[4];
#pragma unroll
      for (int tr = 0; tr < 4; ++tr) acc[tr] = kb;
#pragma unroll
      for (int kk = 0; kk < 4; ++kk)
#pragma unroll
        for (int tr = 0; tr < 4; ++tr)
          acc[tr] = __builtin_amdgcn_mfma_f32_16x16x32_bf16(bw[kk], pa[tr][kk], acc[tr], 0, 0, 0);
#pragma unroll
      for (int tr = 0; tr < 4; ++tr)
        kA[dt][tr] = pack4h(acc[tr][0], acc[tr][1], acc[tr][2], acc[tr][3]);
    }
    {  // V: c = 16+2w+dt, normal -> lane: vdim c*16+l15, tokens tr*16+g*4+r
      const int c = 16 + 2 * w + dt;
      vs8 bw[4];
      const short* wrow = qkv_wb + (c * 16 + l15) * DIMC;
#pragma unroll
      for (int kk = 0; kk < 4; ++kk) bw[kk] = *(const vs8*)(wrow + kk * 32 + g * 8);
      float bv = qkv_b[c * 16 + l15];
      vf4 acc[4];
#pragma unroll
      for (int tr = 0; tr < 4; ++tr) acc[tr] = (vf4){bv, bv, bv, bv};
#pragma unroll
      for (int kk = 0; kk < 4; ++kk)
#pragma unroll
        for (int tr = 0; tr < 4; ++tr)
          acc[tr] = __builtin_amdgcn_mfma_f32_16x16x32_bf16(pa[tr][kk], bw[kk], acc[tr], 0, 0, 0);
#pragma unroll
      for (int tr = 0; tr < 4; ++tr)
        vA[dt][tr] = pack4h(acc[tr][0], acc[tr][1], acc[tr][2], acc[tr][3]);
    }
  }

  // ---- attention: S^T = K·Q^T via K=32 f16 MFMA, bias as C-in; exp with NO max ----
  const short* bpb = bias_bf + w * 4096;
  float inv[4];
  vh4 pB[4][4];  // [trQ][key-tile]
#pragma unroll
  for (int trQ = 0; trQ < 4; ++trQ) {
    const int q = trQ * 16 + l15;
    const vh8 q8 = cat8(qB[0][trQ], qB[1][trQ]);
    vf4 s[4];
#pragma unroll
    for (int tcK = 0; tcK < 4; ++tcK) {
      vf4 cin = unpack_bf4(*(const vu2*)(bpb + q * 64 + tcK * 16 + g * 4));
      s[tcK] = __builtin_amdgcn_mfma_f32_16x16x32_f16(cat8(kA[0][tcK], kA[1][tcK]), q8, cin, 0, 0, 0);
    }
    float sum = 0.f;
    float vv[4][4];
#pragma unroll
    for (int tcK = 0; tcK < 4; ++tcK)
#pragma unroll
      for (int r = 0; r < 4; ++r) { float e = __expf(s[tcK][r]); vv[tcK][r] = e; sum += e; }
    // sum reduction: parallel branch; inv needed only at O-write (post-PV)
    sum += __shfl_xor(sum, 16, 64);
    sum += __shfl_xor(sum, 32, 64);
    inv[trQ] = 1.0f / sum;
#pragma unroll
    for (int tcK = 0; tcK < 4; ++tcK)
      pB[trQ][tcK] = pack4h(vv[tcK][0], vv[tcK][1], vv[tcK][2], vv[tcK][3]);
  }

  // ---- PV: O^T = Vt·P^T via K=32 f16 MFMA (unnormalized P) ----
  vf4 oacc[2][4];  // [dt][trQ]: lane: q = trQ*16+l15, d = 32w+dt*16+g*4+r
#pragma unroll
  for (int dt = 0; dt < 2; ++dt)
#pragma unroll
    for (int trQ = 0; trQ < 4; ++trQ) oacc[dt][trQ] = (vf4){0.f, 0.f, 0.f, 0.f};
#pragma unroll
  for (int trQ = 0; trQ < 4; ++trQ)
#pragma unroll
    for (int tp = 0; tp < 2; ++tp) {
      const vh8 p8 = cat8(pB[trQ][2 * tp], pB[trQ][2 * tp + 1]);
      oacc[0][trQ] = __builtin_amdgcn_mfma_f32_16x16x32_f16(cat8(vA[0][2 * tp], vA[0][2 * tp + 1]), p8, oacc[0][trQ], 0, 0, 0);
      oacc[1][trQ] = __builtin_amdgcn_mfma_f32_16x16x32_f16(cat8(vA[1][2 * tp], vA[1][2 * tp + 1]), p8, oacc[1][trQ], 0, 0, 0);
    }

  // ---- hoist GEMM2 weights/bias loads above the barrier ----
  vs8 bw2[2][4];
  vf4 pb2[2];
#pragma unroll
  for (int ci = 0; ci < 2; ++ci) {
    int ct = w + ci * 4;
    const short* wr = proj_wb + (ct * 16 + l15) * DIMC;
#pragma unroll
    for (int kk = 0; kk < 4; ++kk) bw2[ci][kk] = *(const vs8*)(wr + kk * 32 + g * 8);
    pb2[ci] = *(const vf4*)(proj_b + ct * 16 + g * 4);
  }

  // ---- write O (normalized PER-HEAD, bf16) into lds ----
#pragma unroll
  for (int trQ = 0; trQ < 4; ++trQ) {
    const int q = trQ * 16 + l15;
    const float iv = inv[trQ];
#pragma unroll
    for (int dt = 0; dt < 2; ++dt) {
      int db = (w * 32 + dt * 16 + g * 4) * 2;
      vu2 p;
      p[0] = cvtpk(oacc[dt][trQ][0] * iv, oacc[dt][trQ][1] * iv);
      p[1] = cvtpk(oacc[dt][trQ][2] * iv, oacc[dt][trQ][3] * iv);
      *(vu2*)(lds + q * 256 + (db ^ ((q & 7) << 4))) = p;
    }
  }
  __syncthreads();

  // ---- GEMM2 (swapped): out = O @ proj_w^T, proj_b as C-in -> float4 stores ----
  vs8 oa[4][4];
#pragma unroll
  for (int tr = 0; tr < 4; ++tr) {
    int row = tr * 16 + l15;
#pragma unroll
    for (int kk = 0; kk < 4; ++kk)
      oa[tr][kk] = *(const vs8*)(lds + row * 256 + ((kk * 64 + g * 16) ^ ((row & 7) << 4)));
  }
  float* outw = out + (size_t)win * (NTOK * DIMC);
#pragma unroll
  for (int ci = 0; ci < 2; ++ci) {
    int ct = w + ci * 4;
    vf4 acc[4];
#pragma unroll
    for (int tr = 0; tr < 4; ++tr) acc[tr] = pb2[ci];
#pragma unroll
    for (int kk = 0; kk < 4; ++kk)
#pragma unroll
      for (int tr = 0; tr < 4; ++tr)
        acc[tr] = __builtin_amdgcn_mfma_f32_16x16x32_bf16(bw2[ci][kk], oa[tr][kk], acc[tr], 0, 0, 0);
#pragma unroll
    for (int tr = 0; tr < 4; ++tr) {
      int token = tr * 16 + l15;
      if (token < NTOK)
        *(vf4*)(outw + token * DIMC + ct * 16 + g * 4) = acc[tr];
    }
  }
}

extern "C" void kernel_launch(void* const* d_in, const int* in_sizes, int n_in,
                              void* d_out, int out_size, void* d_ws, size_t ws_size,
                              hipStream_t stream) {
  const float* x          = (const float*)d_in[0];
  const float* qkv_w      = (const float*)d_in[1];
  const float* qkv_b      = (const float*)d_in[2];
  const float* proj_w     = (const float*)d_in[3];
  const float* proj_b     = (const float*)d_in[4];
  const float* bias_table = (const float*)d_in[5];
  const int*   rel_index  = (const int*)d_in[6];
  float* out = (float*)d_out;

  short* qkv_wb   = (short*)d_ws;                      // 49152 bf16
  short* proj_wb  = (short*)((char*)d_ws + 98304);     // 16384 bf16
  short* bias_bf  = (short*)((char*)d_ws + 131072);    // 4*64*64 bf16 = 32KB

  prep_kernel<<<320, 256, 0, stream>>>(qkv_w, proj_w, bias_table, rel_index,
                                       qkv_wb, proj_wb, bias_bf);
  win_attn<<<NWIN, 256, 0, stream>>>(x, qkv_b, proj_b, qkv_wb, proj_wb, bias_bf, out);
}

// Round 13
// 115.838 us; speedup vs baseline: 1.0966x; 1.0966x over previous
//
#include <hip/hip_runtime.h>

#define NWIN 4096
#define NTOK 49
#define DIMC 128
#define QK_SCALE 0.17677669529663689f  // 32^-0.5

typedef __attribute__((ext_vector_type(8))) short vs8;        // 8 bf16 (4 VGPRs)
typedef __attribute__((ext_vector_type(4))) float vf4;
typedef __attribute__((ext_vector_type(2))) unsigned vu2;     // 2 packed bf16x2
typedef __attribute__((ext_vector_type(4))) _Float16 vh4;     // 4 f16 (2 VGPRs)
typedef __attribute__((ext_vector_type(8))) _Float16 vh8;     // 8 f16 (4 VGPRs) — K=32 MFMA operand
typedef __attribute__((ext_vector_type(2))) __fp16 vp2;       // cvt_pkrtz result type

// compile-time memory fence: blocks load-CSE (so LDS fragments are re-read, not
// held in VGPRs) at zero runtime cost.
#define NO_CSE() asm volatile("" ::: "memory")

__device__ __forceinline__ unsigned cvtpk(float a, float b) {  // 2xf32 -> packed bf16x2
  unsigned r;
  asm("v_cvt_pk_bf16_f32 %0, %1, %2" : "=v"(r) : "v"(a), "v"(b));
  return r;
}

__device__ __forceinline__ vh4 pack4h(float a0, float a1, float a2, float a3) {
  union { vh4 v; vp2 h[2]; } u;
  u.h[0] = __builtin_amdgcn_cvt_pkrtz(a0, a1);
  u.h[1] = __builtin_amdgcn_cvt_pkrtz(a2, a3);
  return u.v;
}

__device__ __forceinline__ vh8 cat8(vh4 a, vh4 b) {
  union { vh8 v8; vh4 v4[2]; } u;
  u.v4[0] = a; u.v4[1] = b;
  return u.v8;
}

__device__ __forceinline__ vf4 unpack_bf4(vu2 b) {  // 4 packed bf16 -> vf4
  union { unsigned u; float f; } a0, a1, a2, a3;
  a0.u = b[0] << 16; a1.u = b[0] & 0xffff0000u;
  a2.u = b[1] << 16; a3.u = b[1] & 0xffff0000u;
  return (vf4){a0.f, a1.f, a2.f, a3.f};
}

__device__ __forceinline__ short f2bf(float f) {
  union { float f; unsigned u; } x; x.f = f;
  unsigned r = x.u + 0x7fffu + ((x.u >> 16) & 1u);
  return (short)(r >> 16);
}

// ---------------- prep: weights->bf16, bias table -> padded bf16 [4][64][64] ----------------
__global__ void prep_kernel(const float* __restrict__ qkv_w, const float* __restrict__ proj_w,
                            const float* __restrict__ bias_table, const int* __restrict__ rel_index,
                            short* __restrict__ qkv_wb, short* __restrict__ proj_wb,
                            short* __restrict__ bias_bf) {
  int i = blockIdx.x * 256 + threadIdx.x;
  if (i < 49152) qkv_wb[i] = f2bf(qkv_w[i]);
  int j = i - 49152;
  if (j >= 0 && j < 16384) proj_wb[j] = f2bf(proj_w[j]);
  int k = i - 65536;
  if (k >= 0 && k < 16384) {
    int h = k >> 12, rc = k & 4095, r = rc >> 6, c = rc & 63;
    float v = -1e30f;
    if (r < NTOK && c < NTOK) v = bias_table[rel_index[r * NTOK + c] * 4 + h];
    bias_bf[k] = f2bf(v);
  }
}

// ---------------- fused window attention ----------------
// block = 1 window, 4 waves; wave w owns head w END-TO-END.
// VGPR DIET vs R11 (124 VGPR -> target <=102 for 5 waves/SIMD):
//  - X fragments re-read from LDS per GEMM1 tile; NO_CSE() fence per tile stops
//    the compiler folding the 6x-reused loads back into a held 64-reg array.
//  - attention fused per q-row-tile: QK -> exp(no max) -> sum(shfl, parallel
//    branch) -> pack P -> PV -> normalized O-write. pB 32->8, oacc 32->8 regs.
//  - GEMM2 reads O fragments per-ci with NO_CSE() (not held 64).
// No-max softmax (|S|<~7), per-head normalization at O-write, bias as C-in,
// K=32 f16 attention MFMAs. LDS 16KB: X staging then O exchange. 3 barriers:
// post-staging / post-GEMM1 (X dead) / post-O-write.
__launch_bounds__(256)
__global__ void win_attn(const float* __restrict__ x,
                         const float* __restrict__ qkv_b,
                         const float* __restrict__ proj_b,
                         const short* __restrict__ qkv_wb,
                         const short* __restrict__ proj_wb,
                         const short* __restrict__ bias_bf,
                         float* __restrict__ out) {
  __shared__ __align__(16) char lds[16384];

  const int tid  = threadIdx.x;
  const int lane = tid & 63;
  const int w    = tid >> 6;
  const int l15  = lane & 15;
  const int g    = lane >> 4;
  const int win  = blockIdx.x;

  // ---- stage X -> lds (bf16, swizzled): issue loads, then cvt+write ----
  const float* xw = x + (size_t)win * (NTOK * DIMC);
  vf4 xa[4], xb[4];
  int srow[4], sc16[4];
#pragma unroll
  for (int it = 0; it < 4; ++it) {
    int chunk = tid + it * 256;
    srow[it] = chunk >> 4; sc16[it] = chunk & 15;
    if (srow[it] < NTOK) {
      const float* src = xw + srow[it] * DIMC + sc16[it] * 8;
      xa[it] = *(const vf4*)src;
      xb[it] = *(const vf4*)(src + 4);
    }
  }
#pragma unroll
  for (int it = 0; it < 4; ++it) {
    union { vs8 s; unsigned u[4]; } pk;
    if (srow[it] < NTOK) {
      pk.u[0] = cvtpk(xa[it].x, xa[it].y); pk.u[1] = cvtpk(xa[it].z, xa[it].w);
      pk.u[2] = cvtpk(xb[it].x, xb[it].y); pk.u[3] = cvtpk(xb[it].z, xb[it].w);
    } else {
      pk.u[0] = pk.u[1] = pk.u[2] = pk.u[3] = 0u;
    }
    *(vs8*)(lds + srow[it] * 256 + ((sc16[it] * 16) ^ ((srow[it] & 7) << 4))) = pk.s;
  }
  __syncthreads();

  // ---- GEMM1: wave w computes head w's Q, K (swapped) and V (normal) ----
  // X fragments read from LDS inside each tile (NO_CSE keeps them transient).
  vh4 qB[2][4], kA[2][4], vA[2][4];   // [dim-tile dt][token-tile]
#pragma unroll
  for (int dt = 0; dt < 2; ++dt) {
    {  // Q: c = 2w+dt, swapped -> lane: token=tr*16+l15, dims c*16+g*4+r
      const int c = 2 * w + dt;
      vs8 bw[4];
      const short* wrow = qkv_wb + (c * 16 + l15) * DIMC;
#pragma unroll
      for (int kk = 0; kk < 4; ++kk) bw[kk] = *(const vs8*)(wrow + kk * 32 + g * 8);
      vf4 qb = *(const vf4*)(qkv_b + c * 16 + g * 4);
      NO_CSE();
      vf4 acc[4];
#pragma unroll
      for (int tr = 0; tr < 4; ++tr) acc[tr] = qb;
#pragma unroll
      for (int kk = 0; kk < 4; ++kk)
#pragma unroll
        for (int tr = 0; tr < 4; ++tr) {
          int row = tr * 16 + l15;
          vs8 f = *(const vs8*)(lds + row * 256 + ((kk * 64 + g * 16) ^ ((row & 7) << 4)));
          acc[tr] = __builtin_amdgcn_mfma_f32_16x16x32_bf16(bw[kk], f, acc[tr], 0, 0, 0);
        }
#pragma unroll
      for (int tr = 0; tr < 4; ++tr)
        qB[dt][tr] = pack4h(acc[tr][0] * QK_SCALE, acc[tr][1] * QK_SCALE,
                            acc[tr][2] * QK_SCALE, acc[tr][3] * QK_SCALE);
    }
    {  // K: c = 8+2w+dt, swapped
      const int c = 8 + 2 * w + dt;
      vs8 bw[4];
      const short* wrow = qkv_wb + (c * 16 + l15) * DIMC;
#pragma unroll
      for (int kk = 0; kk < 4; ++kk) bw[kk] = *(const vs8*)(wrow + kk * 32 + g * 8);
      vf4 kb = *(const vf4*)(qkv_b + c * 16 + g * 4);
      NO_CSE();
      vf4 acc[4];
#pragma unroll
      for (int tr = 0; tr < 4; ++tr) acc[tr] = kb;
#pragma unroll
      for (int kk = 0; kk < 4; ++kk)
#pragma unroll
        for (int tr = 0; tr < 4; ++tr) {
          int row = tr * 16 + l15;
          vs8 f = *(const vs8*)(lds + row * 256 + ((kk * 64 + g * 16) ^ ((row & 7) << 4)));
          acc[tr] = __builtin_amdgcn_mfma_f32_16x16x32_bf16(bw[kk], f, acc[tr], 0, 0, 0);
        }
#pragma unroll
      for (int tr = 0; tr < 4; ++tr)
        kA[dt][tr] = pack4h(acc[tr][0], acc[tr][1], acc[tr][2], acc[tr][3]);
    }
    {  // V: c = 16+2w+dt, normal -> lane: vdim c*16+l15, tokens tr*16+g*4+r
      const int c = 16 + 2 * w + dt;
      vs8 bw[4];
      const short* wrow = qkv_wb + (c * 16 + l15) * DIMC;
#pragma unroll
      for (int kk = 0; kk < 4; ++kk) bw[kk] = *(const vs8*)(wrow + kk * 32 + g * 8);
      float bv = qkv_b[c * 16 + l15];
      NO_CSE();
      vf4 acc[4];
#pragma unroll
      for (int tr = 0; tr < 4; ++tr) acc[tr] = (vf4){bv, bv, bv, bv};
#pragma unroll
      for (int kk = 0; kk < 4; ++kk)
#pragma unroll
        for (int tr = 0; tr < 4; ++tr) {
          int row = tr * 16 + l15;
          vs8 f = *(const vs8*)(lds + row * 256 + ((kk * 64 + g * 16) ^ ((row & 7) << 4)));
          acc[tr] = __builtin_amdgcn_mfma_f32_16x16x32_bf16(f, bw[kk], acc[tr], 0, 0, 0);
        }
#pragma unroll
      for (int tr = 0; tr < 4; ++tr)
        vA[dt][tr] = pack4h(acc[tr][0], acc[tr][1], acc[tr][2], acc[tr][3]);
    }
  }
  __syncthreads();  // X dead in LDS -> buffer reusable for O exchange

  // ---- attention fused per q-row-tile: QK -> exp -> sum(parallel) -> PV -> O ----
  const short* bpb = bias_bf + w * 4096;
#pragma unroll
  for (int trQ = 0; trQ < 4; ++trQ) {
    const int q = trQ * 16 + l15;
    const vh8 q8 = cat8(qB[0][trQ], qB[1][trQ]);
    vf4 s[4];
#pragma unroll
    for (int tcK = 0; tcK < 4; ++tcK) {
      vf4 cin = unpack_bf4(*(const vu2*)(bpb + q * 64 + tcK * 16 + g * 4));
      s[tcK] = __builtin_amdgcn_mfma_f32_16x16x32_f16(cat8(kA[0][tcK], kA[1][tcK]), q8, cin, 0, 0, 0);
    }
    float sum = 0.f;
#pragma unroll
    for (int tcK = 0; tcK < 4; ++tcK)
#pragma unroll
      for (int r = 0; r < 4; ++r) { float e = __expf(s[tcK][r]); s[tcK][r] = e; sum += e; }
    sum += __shfl_xor(sum, 16, 64);   // parallel branch: inv needed only at O-write
    sum += __shfl_xor(sum, 32, 64);
    float iv = 1.0f / sum;
    vh4 pBl[4];
#pragma unroll
    for (int tcK = 0; tcK < 4; ++tcK)
      pBl[tcK] = pack4h(s[tcK][0], s[tcK][1], s[tcK][2], s[tcK][3]);
    // PV for this trQ only (oacc = 8 regs)
    vf4 o0 = (vf4){0.f, 0.f, 0.f, 0.f}, o1 = (vf4){0.f, 0.f, 0.f, 0.f};
#pragma unroll
    for (int tp = 0; tp < 2; ++tp) {
      const vh8 p8 = cat8(pBl[2 * tp], pBl[2 * tp + 1]);
      o0 = __builtin_amdgcn_mfma_f32_16x16x32_f16(cat8(vA[0][2 * tp], vA[0][2 * tp + 1]), p8, o0, 0, 0, 0);
      o1 = __builtin_amdgcn_mfma_f32_16x16x32_f16(cat8(vA[1][2 * tp], vA[1][2 * tp + 1]), p8, o1, 0, 0, 0);
    }
    // write O (normalized per-head, bf16) into lds (X region, dead)
    {
      int db0 = (w * 32 + g * 4) * 2;
      vu2 p;
      p[0] = cvtpk(o0[0] * iv, o0[1] * iv);
      p[1] = cvtpk(o0[2] * iv, o0[3] * iv);
      *(vu2*)(lds + q * 256 + (db0 ^ ((q & 7) << 4))) = p;
      int db1 = (w * 32 + 16 + g * 4) * 2;
      p[0] = cvtpk(o1[0] * iv, o1[1] * iv);
      p[1] = cvtpk(o1[2] * iv, o1[3] * iv);
      *(vu2*)(lds + q * 256 + (db1 ^ ((q & 7) << 4))) = p;
    }
  }
  __syncthreads();

  // ---- GEMM2 (swapped): out = O @ proj_w^T, proj_b as C-in; O frags per-ci ----
  float* outw = out + (size_t)win * (NTOK * DIMC);
#pragma unroll
  for (int ci = 0; ci < 2; ++ci) {
    int ct = w + ci * 4;
    vs8 bw2[4];
    const short* wr = proj_wb + (ct * 16 + l15) * DIMC;
#pragma unroll
    for (int kk = 0; kk < 4; ++kk) bw2[kk] = *(const vs8*)(wr + kk * 32 + g * 8);
    vf4 pb = *(const vf4*)(proj_b + ct * 16 + g * 4);
    NO_CSE();
    vf4 acc[4];
#pragma unroll
    for (int tr = 0; tr < 4; ++tr) acc[tr] = pb;
#pragma unroll
    for (int kk = 0; kk < 4; ++kk)
#pragma unroll
      for (int tr = 0; tr < 4; ++tr) {
        int row = tr * 16 + l15;
        vs8 f = *(const vs8*)(lds + row * 256 + ((kk * 64 + g * 16) ^ ((row & 7) << 4)));
        acc[tr] = __builtin_amdgcn_mfma_f32_16x16x32_bf16(bw2[kk], f, acc[tr], 0, 0, 0);
      }
#pragma unroll
    for (int tr = 0; tr < 4; ++tr) {
      int token = tr * 16 + l15;
      if (token < NTOK)
        *(vf4*)(outw + token * DIMC + ct * 16 + g * 4) = acc[tr];
    }
  }
}

extern "C" void kernel_launch(void* const* d_in, const int* in_sizes, int n_in,
                              void* d_out, int out_size, void* d_ws, size_t ws_size,
                              hipStream_t stream) {
  const float* x          = (const float*)d_in[0];
  const float* qkv_w      = (const float*)d_in[1];
  const float* qkv_b      = (const float*)d_in[2];
  const float* proj_w     = (const float*)d_in[3];
  const float* proj_b     = (const float*)d_in[4];
  const float* bias_table = (const float*)d_in[5];
  const int*   rel_index  = (const int*)d_in[6];
  float* out = (float*)d_out;

  short* qkv_wb   = (short*)d_ws;                      // 49152 bf16
  short* proj_wb  = (short*)((char*)d_ws + 98304);     // 16384 bf16
  short* bias_bf  = (short*)((char*)d_ws + 131072);    // 4*64*64 bf16 = 32KB

  prep_kernel<<<320, 256, 0, stream>>>(qkv_w, proj_w, bias_table, rel_index,
                                       qkv_wb, proj_wb, bias_bf);
  win_attn<<<NWIN, 256, 0, stream>>>(x, qkv_b, proj_b, qkv_wb, proj_wb, bias_bf, out);
}

// Round 14
// 82.478 us; speedup vs baseline: 1.5401x; 1.4045x over previous
//
#include <hip/hip_runtime.h>

#define NWIN 4096
#define NTOK 49
#define DIMC 128
#define QK_SCALE 0.17677669529663689f  // 32^-0.5

typedef __attribute__((ext_vector_type(8))) short vs8;        // 8 bf16 (4 VGPRs)
typedef __attribute__((ext_vector_type(4))) float vf4;
typedef __attribute__((ext_vector_type(2))) unsigned vu2;     // 2 packed bf16x2
typedef __attribute__((ext_vector_type(4))) _Float16 vh4;     // 4 f16 (2 VGPRs)
typedef __attribute__((ext_vector_type(8))) _Float16 vh8;     // 8 f16 (4 VGPRs) — K=32 MFMA operand
typedef __attribute__((ext_vector_type(2))) __fp16 vp2;       // cvt_pkrtz result type

#define NO_CSE() asm volatile("" ::: "memory")

__device__ __forceinline__ unsigned cvtpk(float a, float b) {  // 2xf32 -> packed bf16x2
  unsigned r;
  asm("v_cvt_pk_bf16_f32 %0, %1, %2" : "=v"(r) : "v"(a), "v"(b));
  return r;
}

__device__ __forceinline__ vh4 pack4h(float a0, float a1, float a2, float a3) {
  union { vh4 v; vp2 h[2]; } u;
  u.h[0] = __builtin_amdgcn_cvt_pkrtz(a0, a1);
  u.h[1] = __builtin_amdgcn_cvt_pkrtz(a2, a3);
  return u.v;
}

__device__ __forceinline__ vh8 cat8(vh4 a, vh4 b) {
  union { vh8 v8; vh4 v4[2]; } u;
  u.v4[0] = a; u.v4[1] = b;
  return u.v8;
}

__device__ __forceinline__ vf4 unpack_bf4(vu2 b) {  // 4 packed bf16 -> vf4
  union { unsigned u; float f; } a0, a1, a2, a3;
  a0.u = b[0] << 16; a1.u = b[0] & 0xffff0000u;
  a2.u = b[1] << 16; a3.u = b[1] & 0xffff0000u;
  return (vf4){a0.f, a1.f, a2.f, a3.f};
}

__device__ __forceinline__ short f2bf(float f) {
  union { float f; unsigned u; } x; x.f = f;
  unsigned r = x.u + 0x7fffu + ((x.u >> 16) & 1u);
  return (short)(r >> 16);
}

// ---------------- prep: weights->bf16, bias table -> padded bf16 [4][64][64] ----------------
__global__ void prep_kernel(const float* __restrict__ qkv_w, const float* __restrict__ proj_w,
                            const float* __restrict__ bias_table, const int* __restrict__ rel_index,
                            short* __restrict__ qkv_wb, short* __restrict__ proj_wb,
                            short* __restrict__ bias_bf) {
  int i = blockIdx.x * 256 + threadIdx.x;
  if (i < 49152) qkv_wb[i] = f2bf(qkv_w[i]);
  int j = i - 49152;
  if (j >= 0 && j < 16384) proj_wb[j] = f2bf(proj_w[j]);
  int k = i - 65536;
  if (k >= 0 && k < 16384) {
    int h = k >> 12, rc = k & 4095, r = rc >> 6, c = rc & 63;
    float v = -1e30f;
    if (r < NTOK && c < NTOK) v = bias_table[rel_index[r * NTOK + c] * 4 + h];
    bias_bf[k] = f2bf(v);
  }
}

// ---------------- fused window attention — TWO windows per block ----------------
// block = 2 windows (A,B), 4 waves; wave w owns head w of BOTH windows as two
// independent interleaved dependency chains (2x ILP per wave — R13 showed
// occupancy is saturated; per-wave chain latency is the limiter).
// Weights/biases loaded ONCE per tile, shared by both windows' MFMAs.
// R13's VGPR diet retained: X frags re-read from LDS w/ NO_CSE, attention fused
// per q-row-tile, no-max softmax, per-head normalization at O-write.
// LDS 32KB = 2 x 16KB halves (X staging then O exchange per window). 3 barriers.
__launch_bounds__(256)
__global__ void win_attn(const float* __restrict__ x,
                         const float* __restrict__ qkv_b,
                         const float* __restrict__ proj_b,
                         const short* __restrict__ qkv_wb,
                         const short* __restrict__ proj_wb,
                         const short* __restrict__ bias_bf,
                         float* __restrict__ out) {
  __shared__ __align__(16) char lds[32768];
  char* const ldsA = lds;
  char* const ldsB = lds + 16384;

  const int tid  = threadIdx.x;
  const int lane = tid & 63;
  const int w    = tid >> 6;
  const int l15  = lane & 15;
  const int g    = lane >> 4;
  const int winA = blockIdx.x * 2;

  // ---- stage both windows: issue all loads, then cvt+write ----
  const float* xwA = x + (size_t)winA * (NTOK * DIMC);
  const float* xwB = xwA + NTOK * DIMC;
  vf4 aA[4], bA[4], aB[4], bB[4];
  int srow[4], sc16[4];
#pragma unroll
  for (int it = 0; it < 4; ++it) {
    int chunk = tid + it * 256;
    srow[it] = chunk >> 4; sc16[it] = chunk & 15;
    if (srow[it] < NTOK) {
      const float* sA = xwA + srow[it] * DIMC + sc16[it] * 8;
      const float* sB = xwB + srow[it] * DIMC + sc16[it] * 8;
      aA[it] = *(const vf4*)sA; bA[it] = *(const vf4*)(sA + 4);
      aB[it] = *(const vf4*)sB; bB[it] = *(const vf4*)(sB + 4);
    }
  }
#pragma unroll
  for (int it = 0; it < 4; ++it) {
    union { vs8 s; unsigned u[4]; } pA, pB;
    if (srow[it] < NTOK) {
      pA.u[0] = cvtpk(aA[it].x, aA[it].y); pA.u[1] = cvtpk(aA[it].z, aA[it].w);
      pA.u[2] = cvtpk(bA[it].x, bA[it].y); pA.u[3] = cvtpk(bA[it].z, bA[it].w);
      pB.u[0] = cvtpk(aB[it].x, aB[it].y); pB.u[1] = cvtpk(aB[it].z, aB[it].w);
      pB.u[2] = cvtpk(bB[it].x, bB[it].y); pB.u[3] = cvtpk(bB[it].z, bB[it].w);
    } else {
      pA.u[0] = pA.u[1] = pA.u[2] = pA.u[3] = 0u;
      pB.u[0] = pB.u[1] = pB.u[2] = pB.u[3] = 0u;
    }
    int off = srow[it] * 256 + ((sc16[it] * 16) ^ ((srow[it] & 7) << 4));
    *(vs8*)(ldsA + off) = pA.s;
    *(vs8*)(ldsB + off) = pB.s;
  }
  __syncthreads();

  // ---- GEMM1: head w's Q,K (swapped) and V (normal) for BOTH windows ----
  vh4 qBA[2][4], qBB[2][4], kAA[2][4], kAB[2][4], vAA[2][4], vAB[2][4];
#pragma unroll
  for (int dt = 0; dt < 2; ++dt) {
    {  // Q: c = 2w+dt
      const int c = 2 * w + dt;
      vs8 bw[4];
      const short* wrow = qkv_wb + (c * 16 + l15) * DIMC;
#pragma unroll
      for (int kk = 0; kk < 4; ++kk) bw[kk] = *(const vs8*)(wrow + kk * 32 + g * 8);
      vf4 qb = *(const vf4*)(qkv_b + c * 16 + g * 4);
      NO_CSE();
      vf4 accA[4], accB[4];
#pragma unroll
      for (int tr = 0; tr < 4; ++tr) { accA[tr] = qb; accB[tr] = qb; }
#pragma unroll
      for (int kk = 0; kk < 4; ++kk)
#pragma unroll
        for (int tr = 0; tr < 4; ++tr) {
          int row = tr * 16 + l15;
          int off = row * 256 + ((kk * 64 + g * 16) ^ ((row & 7) << 4));
          accA[tr] = __builtin_amdgcn_mfma_f32_16x16x32_bf16(bw[kk], *(const vs8*)(ldsA + off), accA[tr], 0, 0, 0);
          accB[tr] = __builtin_amdgcn_mfma_f32_16x16x32_bf16(bw[kk], *(const vs8*)(ldsB + off), accB[tr], 0, 0, 0);
        }
#pragma unroll
      for (int tr = 0; tr < 4; ++tr) {
        qBA[dt][tr] = pack4h(accA[tr][0] * QK_SCALE, accA[tr][1] * QK_SCALE,
                             accA[tr][2] * QK_SCALE, accA[tr][3] * QK_SCALE);
        qBB[dt][tr] = pack4h(accB[tr][0] * QK_SCALE, accB[tr][1] * QK_SCALE,
                             accB[tr][2] * QK_SCALE, accB[tr][3] * QK_SCALE);
      }
    }
    {  // K: c = 8+2w+dt
      const int c = 8 + 2 * w + dt;
      vs8 bw[4];
      const short* wrow = qkv_wb + (c * 16 + l15) * DIMC;
#pragma unroll
      for (int kk = 0; kk < 4; ++kk) bw[kk] = *(const vs8*)(wrow + kk * 32 + g * 8);
      vf4 kb = *(const vf4*)(qkv_b + c * 16 + g * 4);
      NO_CSE();
      vf4 accA[4], accB[4];
#pragma unroll
      for (int tr = 0; tr < 4; ++tr) { accA[tr] = kb; accB[tr] = kb; }
#pragma unroll
      for (int kk = 0; kk < 4; ++kk)
#pragma unroll
        for (int tr = 0; tr < 4; ++tr) {
          int row = tr * 16 + l15;
          int off = row * 256 + ((kk * 64 + g * 16) ^ ((row & 7) << 4));
          accA[tr] = __builtin_amdgcn_mfma_f32_16x16x32_bf16(bw[kk], *(const vs8*)(ldsA + off), accA[tr], 0, 0, 0);
          accB[tr] = __builtin_amdgcn_mfma_f32_16x16x32_bf16(bw[kk], *(const vs8*)(ldsB + off), accB[tr], 0, 0, 0);
        }
#pragma unroll
      for (int tr = 0; tr < 4; ++tr) {
        kAA[dt][tr] = pack4h(accA[tr][0], accA[tr][1], accA[tr][2], accA[tr][3]);
        kAB[dt][tr] = pack4h(accB[tr][0], accB[tr][1], accB[tr][2], accB[tr][3]);
      }
    }
    {  // V: c = 16+2w+dt (normal orientation)
      const int c = 16 + 2 * w + dt;
      vs8 bw[4];
      const short* wrow = qkv_wb + (c * 16 + l15) * DIMC;
#pragma unroll
      for (int kk = 0; kk < 4; ++kk) bw[kk] = *(const vs8*)(wrow + kk * 32 + g * 8);
      float bv = qkv_b[c * 16 + l15];
      NO_CSE();
      vf4 accA[4], accB[4];
#pragma unroll
      for (int tr = 0; tr < 4; ++tr) { accA[tr] = (vf4){bv, bv, bv, bv}; accB[tr] = accA[tr]; }
#pragma unroll
      for (int kk = 0; kk < 4; ++kk)
#pragma unroll
        for (int tr = 0; tr < 4; ++tr) {
          int row = tr * 16 + l15;
          int off = row * 256 + ((kk * 64 + g * 16) ^ ((row & 7) << 4));
          accA[tr] = __builtin_amdgcn_mfma_f32_16x16x32_bf16(*(const vs8*)(ldsA + off), bw[kk], accA[tr], 0, 0, 0);
          accB[tr] = __builtin_amdgcn_mfma_f32_16x16x32_bf16(*(const vs8*)(ldsB + off), bw[kk], accB[tr], 0, 0, 0);
        }
#pragma unroll
      for (int tr = 0; tr < 4; ++tr) {
        vAA[dt][tr] = pack4h(accA[tr][0], accA[tr][1], accA[tr][2], accA[tr][3]);
        vAB[dt][tr] = pack4h(accB[tr][0], accB[tr][1], accB[tr][2], accB[tr][3]);
      }
    }
  }
  __syncthreads();  // X dead in both halves -> reusable for O exchange

  // ---- attention fused per q-row-tile, both windows interleaved ----
  const short* bpb = bias_bf + w * 4096;
#pragma unroll
  for (int trQ = 0; trQ < 4; ++trQ) {
    const int q = trQ * 16 + l15;
    const vh8 q8A = cat8(qBA[0][trQ], qBA[1][trQ]);
    const vh8 q8B = cat8(qBB[0][trQ], qBB[1][trQ]);
    vf4 sA[4], sB[4];
#pragma unroll
    for (int tcK = 0; tcK < 4; ++tcK) {
      vf4 cin = unpack_bf4(*(const vu2*)(bpb + q * 64 + tcK * 16 + g * 4));  // shared A/B
      sA[tcK] = __builtin_amdgcn_mfma_f32_16x16x32_f16(cat8(kAA[0][tcK], kAA[1][tcK]), q8A, cin, 0, 0, 0);
      sB[tcK] = __builtin_amdgcn_mfma_f32_16x16x32_f16(cat8(kAB[0][tcK], kAB[1][tcK]), q8B, cin, 0, 0, 0);
    }
    float sumA = 0.f, sumB = 0.f;
#pragma unroll
    for (int tcK = 0; tcK < 4; ++tcK)
#pragma unroll
      for (int r = 0; r < 4; ++r) {
        float eA = __expf(sA[tcK][r]); sA[tcK][r] = eA; sumA += eA;
        float eB = __expf(sB[tcK][r]); sB[tcK][r] = eB; sumB += eB;
      }
    sumA += __shfl_xor(sumA, 16, 64);
    sumB += __shfl_xor(sumB, 16, 64);
    sumA += __shfl_xor(sumA, 32, 64);
    sumB += __shfl_xor(sumB, 32, 64);
    float ivA = 1.0f / sumA, ivB = 1.0f / sumB;
    vh4 pA[4], pB[4];
#pragma unroll
    for (int tcK = 0; tcK < 4; ++tcK) {
      pA[tcK] = pack4h(sA[tcK][0], sA[tcK][1], sA[tcK][2], sA[tcK][3]);
      pB[tcK] = pack4h(sB[tcK][0], sB[tcK][1], sB[tcK][2], sB[tcK][3]);
    }
    vf4 o0A = (vf4){0.f,0.f,0.f,0.f}, o1A = o0A, o0B = o0A, o1B = o0A;
#pragma unroll
    for (int tp = 0; tp < 2; ++tp) {
      const vh8 p8A = cat8(pA[2 * tp], pA[2 * tp + 1]);
      const vh8 p8B = cat8(pB[2 * tp], pB[2 * tp + 1]);
      o0A = __builtin_amdgcn_mfma_f32_16x16x32_f16(cat8(vAA[0][2 * tp], vAA[0][2 * tp + 1]), p8A, o0A, 0, 0, 0);
      o0B = __builtin_amdgcn_mfma_f32_16x16x32_f16(cat8(vAB[0][2 * tp], vAB[0][2 * tp + 1]), p8B, o0B, 0, 0, 0);
      o1A = __builtin_amdgcn_mfma_f32_16x16x32_f16(cat8(vAA[1][2 * tp], vAA[1][2 * tp + 1]), p8A, o1A, 0, 0, 0);
      o1B = __builtin_amdgcn_mfma_f32_16x16x32_f16(cat8(vAB[1][2 * tp], vAB[1][2 * tp + 1]), p8B, o1B, 0, 0, 0);
    }
    {
      int db0 = (w * 32 + g * 4) * 2;
      int db1 = (w * 32 + 16 + g * 4) * 2;
      int o0 = q * 256 + (db0 ^ ((q & 7) << 4));
      int o1 = q * 256 + (db1 ^ ((q & 7) << 4));
      vu2 p;
      p[0] = cvtpk(o0A[0] * ivA, o0A[1] * ivA); p[1] = cvtpk(o0A[2] * ivA, o0A[3] * ivA);
      *(vu2*)(ldsA + o0) = p;
      p[0] = cvtpk(o1A[0] * ivA, o1A[1] * ivA); p[1] = cvtpk(o1A[2] * ivA, o1A[3] * ivA);
      *(vu2*)(ldsA + o1) = p;
      p[0] = cvtpk(o0B[0] * ivB, o0B[1] * ivB); p[1] = cvtpk(o0B[2] * ivB, o0B[3] * ivB);
      *(vu2*)(ldsB + o0) = p;
      p[0] = cvtpk(o1B[0] * ivB, o1B[1] * ivB); p[1] = cvtpk(o1B[2] * ivB, o1B[3] * ivB);
      *(vu2*)(ldsB + o1) = p;
    }
  }
  __syncthreads();

  // ---- GEMM2 (swapped) for both windows; weights shared ----
  float* outA = out + (size_t)winA * (NTOK * DIMC);
  float* outB = outA + NTOK * DIMC;
#pragma unroll
  for (int ci = 0; ci < 2; ++ci) {
    int ct = w + ci * 4;
    vs8 bw2[4];
    const short* wr = proj_wb + (ct * 16 + l15) * DIMC;
#pragma unroll
    for (int kk = 0; kk < 4; ++kk) bw2[kk] = *(const vs8*)(wr + kk * 32 + g * 8);
    vf4 pb = *(const vf4*)(proj_b + ct * 16 + g * 4);
    NO_CSE();
    vf4 accA[4], accB[4];
#pragma unroll
    for (int tr = 0; tr < 4; ++tr) { accA[tr] = pb; accB[tr] = pb; }
#pragma unroll
    for (int kk = 0; kk < 4; ++kk)
#pragma unroll
      for (int tr = 0; tr < 4; ++tr) {
        int row = tr * 16 + l15;
        int off = row * 256 + ((kk * 64 + g * 16) ^ ((row & 7) << 4));
        accA[tr] = __builtin_amdgcn_mfma_f32_16x16x32_bf16(bw2[kk], *(const vs8*)(ldsA + off), accA[tr], 0, 0, 0);
        accB[tr] = __builtin_amdgcn_mfma_f32_16x16x32_bf16(bw2[kk], *(const vs8*)(ldsB + off), accB[tr], 0, 0, 0);
      }
#pragma unroll
    for (int tr = 0; tr < 4; ++tr) {
      int token = tr * 16 + l15;
      if (token < NTOK) {
        *(vf4*)(outA + token * DIMC + ct * 16 + g * 4) = accA[tr];
        *(vf4*)(outB + token * DIMC + ct * 16 + g * 4) = accB[tr];
      }
    }
  }
}

extern "C" void kernel_launch(void* const* d_in, const int* in_sizes, int n_in,
                              void* d_out, int out_size, void* d_ws, size_t ws_size,
                              hipStream_t stream) {
  const float* x          = (const float*)d_in[0];
  const float* qkv_w      = (const float*)d_in[1];
  const float* qkv_b      = (const float*)d_in[2];
  const float* proj_w     = (const float*)d_in[3];
  const float* proj_b     = (const float*)d_in[4];
  const float* bias_table = (const float*)d_in[5];
  const int*   rel_index  = (const int*)d_in[6];
  float* out = (float*)d_out;

  short* qkv_wb   = (short*)d_ws;                      // 49152 bf16
  short* proj_wb  = (short*)((char*)d_ws + 98304);     // 16384 bf16
  short* bias_bf  = (short*)((char*)d_ws + 131072);    // 4*64*64 bf16 = 32KB

  prep_kernel<<<320, 256, 0, stream>>>(qkv_w, proj_w, bias_table, rel_index,
                                       qkv_wb, proj_wb, bias_bf);
  win_attn<<<NWIN / 2, 256, 0, stream>>>(x, qkv_b, proj_b, qkv_wb, proj_wb, bias_bf, out);
}

// Round 15
// 81.071 us; speedup vs baseline: 1.5668x; 1.0173x over previous
//
#include <hip/hip_runtime.h>

#define NWIN 4096
#define NTOK 49
#define DIMC 128
#define QK_SCALE 0.17677669529663689f  // 32^-0.5

typedef __attribute__((ext_vector_type(8))) short vs8;        // 8 bf16 (4 VGPRs)
typedef __attribute__((ext_vector_type(4))) float vf4;
typedef __attribute__((ext_vector_type(2))) unsigned vu2;     // 2 packed bf16x2
typedef __attribute__((ext_vector_type(4))) _Float16 vh4;     // 4 f16 (2 VGPRs)
typedef __attribute__((ext_vector_type(8))) _Float16 vh8;     // 8 f16 (4 VGPRs) — K=32 MFMA operand
typedef __attribute__((ext_vector_type(2))) __fp16 vp2;       // cvt_pkrtz result type

#define NO_CSE() asm volatile("" ::: "memory")

__device__ __forceinline__ unsigned cvtpk(float a, float b) {  // 2xf32 -> packed bf16x2
  unsigned r;
  asm("v_cvt_pk_bf16_f32 %0, %1, %2" : "=v"(r) : "v"(a), "v"(b));
  return r;
}

__device__ __forceinline__ vh4 pack4h(float a0, float a1, float a2, float a3) {
  union { vh4 v; vp2 h[2]; } u;
  u.h[0] = __builtin_amdgcn_cvt_pkrtz(a0, a1);
  u.h[1] = __builtin_amdgcn_cvt_pkrtz(a2, a3);
  return u.v;
}

__device__ __forceinline__ vh8 cat8(vh4 a, vh4 b) {
  union { vh8 v8; vh4 v4[2]; } u;
  u.v4[0] = a; u.v4[1] = b;
  return u.v8;
}

__device__ __forceinline__ vf4 unpack_bf4(vu2 b) {  // 4 packed bf16 -> vf4
  union { unsigned u; float f; } a0, a1, a2, a3;
  a0.u = b[0] << 16; a1.u = b[0] & 0xffff0000u;
  a2.u = b[1] << 16; a3.u = b[1] & 0xffff0000u;
  return (vf4){a0.f, a1.f, a2.f, a3.f};
}

__device__ __forceinline__ short f2bf(float f) {
  union { float f; unsigned u; } x; x.f = f;
  unsigned r = x.u + 0x7fffu + ((x.u >> 16) & 1u);
  return (short)(r >> 16);
}

// ---------------- prep: weights->bf16, bias table -> padded bf16 [4][64][64] ----------------
__global__ void prep_kernel(const float* __restrict__ qkv_w, const float* __restrict__ proj_w,
                            const float* __restrict__ bias_table, const int* __restrict__ rel_index,
                            short* __restrict__ qkv_wb, short* __restrict__ proj_wb,
                            short* __restrict__ bias_bf) {
  int i = blockIdx.x * 256 + threadIdx.x;
  if (i < 49152) qkv_wb[i] = f2bf(qkv_w[i]);
  int j = i - 49152;
  if (j >= 0 && j < 16384) proj_wb[j] = f2bf(proj_w[j]);
  int k = i - 65536;
  if (k >= 0 && k < 16384) {
    int h = k >> 12, rc = k & 4095, r = rc >> 6, c = rc & 63;
    float v = -1e30f;
    if (r < NTOK && c < NTOK) v = bias_table[rel_index[r * NTOK + c] * 4 + h];
    bias_bf[k] = f2bf(v);
  }
}

// ---------------- fused window attention — TWO windows per block, pipelined loads ----------------
// block = 2 windows (A,B), 4 waves; wave w owns head w of BOTH windows (2x ILP, R14).
// NEW vs R14: 2-stage software pipelines so load latency hides under MFMAs even
// with the NO_CSE fences: (1) GEMM1 flat 6-tile loop with next-tile weight
// prefetch; (2) attention bias (cin) prefetched one trQ ahead; (3) GEMM2
// weights loaded above the final barrier.
// No-max softmax, per-head normalization at O-write, bias as C-in, K=32 f16
// attention MFMAs, X frags re-read from LDS (VGPR diet).
// LDS 32KB = 2 x 16KB halves. 3 barriers.
__launch_bounds__(256)
__global__ void win_attn(const float* __restrict__ x,
                         const float* __restrict__ qkv_b,
                         const float* __restrict__ proj_b,
                         const short* __restrict__ qkv_wb,
                         const short* __restrict__ proj_wb,
                         const short* __restrict__ bias_bf,
                         float* __restrict__ out) {
  __shared__ __align__(16) char lds[32768];
  char* const ldsA = lds;
  char* const ldsB = lds + 16384;

  const int tid  = threadIdx.x;
  const int lane = tid & 63;
  const int w    = tid >> 6;
  const int l15  = lane & 15;
  const int g    = lane >> 4;
  const int winA = blockIdx.x * 2;

  // ---- stage both windows: issue all loads, then cvt+write ----
  const float* xwA = x + (size_t)winA * (NTOK * DIMC);
  const float* xwB = xwA + NTOK * DIMC;
  vf4 aA[4], bA[4], aB[4], bB[4];
  int srow[4], sc16[4];
#pragma unroll
  for (int it = 0; it < 4; ++it) {
    int chunk = tid + it * 256;
    srow[it] = chunk >> 4; sc16[it] = chunk & 15;
    if (srow[it] < NTOK) {
      const float* sA = xwA + srow[it] * DIMC + sc16[it] * 8;
      const float* sB = xwB + srow[it] * DIMC + sc16[it] * 8;
      aA[it] = *(const vf4*)sA; bA[it] = *(const vf4*)(sA + 4);
      aB[it] = *(const vf4*)sB; bB[it] = *(const vf4*)(sB + 4);
    }
  }
#pragma unroll
  for (int it = 0; it < 4; ++it) {
    union { vs8 s; unsigned u[4]; } pA, pB;
    if (srow[it] < NTOK) {
      pA.u[0] = cvtpk(aA[it].x, aA[it].y); pA.u[1] = cvtpk(aA[it].z, aA[it].w);
      pA.u[2] = cvtpk(bA[it].x, bA[it].y); pA.u[3] = cvtpk(bA[it].z, bA[it].w);
      pB.u[0] = cvtpk(aB[it].x, aB[it].y); pB.u[1] = cvtpk(aB[it].z, aB[it].w);
      pB.u[2] = cvtpk(bB[it].x, bB[it].y); pB.u[3] = cvtpk(bB[it].z, bB[it].w);
    } else {
      pA.u[0] = pA.u[1] = pA.u[2] = pA.u[3] = 0u;
      pB.u[0] = pB.u[1] = pB.u[2] = pB.u[3] = 0u;
    }
    int off = srow[it] * 256 + ((sc16[it] * 16) ^ ((srow[it] & 7) << 4));
    *(vs8*)(ldsA + off) = pA.s;
    *(vs8*)(ldsB + off) = pB.s;
  }
  __syncthreads();

  // ---- GEMM1: flat 6-tile pipeline. tile j: kind=j%3 (0=Q,1=K,2=V), dt=j/3,
  //      c = 8*kind + 2*w + dt. Next tile's weights prefetched before the fence.
  vh4 qBA[2][4], qBB[2][4], kAA[2][4], kAB[2][4], vAA[2][4], vAB[2][4];
  vs8 bwC[4];
  vf4 qbC = (vf4){0.f, 0.f, 0.f, 0.f};
  float bvC = 0.f;
  {
    const int c0 = 2 * w;  // j=0: Q, dt=0
    const short* wr = qkv_wb + (c0 * 16 + l15) * DIMC;
#pragma unroll
    for (int kk = 0; kk < 4; ++kk) bwC[kk] = *(const vs8*)(wr + kk * 32 + g * 8);
    qbC = *(const vf4*)(qkv_b + c0 * 16 + g * 4);
  }
#pragma unroll
  for (int j = 0; j < 6; ++j) {
    const int kind = j % 3, dt = j / 3;
    // prefetch next tile's weights+bias BEFORE this tile's fence
    vs8 bwN[4];
    vf4 qbN = (vf4){0.f, 0.f, 0.f, 0.f};
    float bvN = 0.f;
    if (j < 5) {
      const int kn = (j + 1) % 3, dn = (j + 1) / 3;
      const int cn = 8 * kn + 2 * w + dn;
      const short* wr = qkv_wb + (cn * 16 + l15) * DIMC;
#pragma unroll
      for (int kk = 0; kk < 4; ++kk) bwN[kk] = *(const vs8*)(wr + kk * 32 + g * 8);
      if (kn == 2) bvN = qkv_b[cn * 16 + l15];
      else         qbN = *(const vf4*)(qkv_b + cn * 16 + g * 4);
    }
    NO_CSE();
    vf4 accA[4], accB[4];
#pragma unroll
    for (int tr = 0; tr < 4; ++tr) {
      accA[tr] = (kind == 2) ? (vf4){bvC, bvC, bvC, bvC} : qbC;
      accB[tr] = accA[tr];
    }
#pragma unroll
    for (int kk = 0; kk < 4; ++kk)
#pragma unroll
      for (int tr = 0; tr < 4; ++tr) {
        int row = tr * 16 + l15;
        int off = row * 256 + ((kk * 64 + g * 16) ^ ((row & 7) << 4));
        vs8 fA = *(const vs8*)(ldsA + off);
        vs8 fB = *(const vs8*)(ldsB + off);
        if (kind == 2) {  // V: normal orientation
          accA[tr] = __builtin_amdgcn_mfma_f32_16x16x32_bf16(fA, bwC[kk], accA[tr], 0, 0, 0);
          accB[tr] = __builtin_amdgcn_mfma_f32_16x16x32_bf16(fB, bwC[kk], accB[tr], 0, 0, 0);
        } else {          // Q/K: swapped
          accA[tr] = __builtin_amdgcn_mfma_f32_16x16x32_bf16(bwC[kk], fA, accA[tr], 0, 0, 0);
          accB[tr] = __builtin_amdgcn_mfma_f32_16x16x32_bf16(bwC[kk], fB, accB[tr], 0, 0, 0);
        }
      }
#pragma unroll
    for (int tr = 0; tr < 4; ++tr) {
      if (kind == 0) {
        qBA[dt][tr] = pack4h(accA[tr][0] * QK_SCALE, accA[tr][1] * QK_SCALE,
                             accA[tr][2] * QK_SCALE, accA[tr][3] * QK_SCALE);
        qBB[dt][tr] = pack4h(accB[tr][0] * QK_SCALE, accB[tr][1] * QK_SCALE,
                             accB[tr][2] * QK_SCALE, accB[tr][3] * QK_SCALE);
      } else if (kind == 1) {
        kAA[dt][tr] = pack4h(accA[tr][0], accA[tr][1], accA[tr][2], accA[tr][3]);
        kAB[dt][tr] = pack4h(accB[tr][0], accB[tr][1], accB[tr][2], accB[tr][3]);
      } else {
        vAA[dt][tr] = pack4h(accA[tr][0], accA[tr][1], accA[tr][2], accA[tr][3]);
        vAB[dt][tr] = pack4h(accB[tr][0], accB[tr][1], accB[tr][2], accB[tr][3]);
      }
    }
#pragma unroll
    for (int kk = 0; kk < 4; ++kk) bwC[kk] = bwN[kk];
    qbC = qbN; bvC = bvN;
  }
  __syncthreads();  // X dead in both halves -> reusable for O exchange

  // ---- attention fused per q-row-tile, both windows interleaved; cin prefetched ----
  const short* bpb = bias_bf + w * 4096;
  vu2 cinC[4];
#pragma unroll
  for (int tcK = 0; tcK < 4; ++tcK)
    cinC[tcK] = *(const vu2*)(bpb + (0 * 16 + l15) * 64 + tcK * 16 + g * 4);
#pragma unroll
  for (int trQ = 0; trQ < 4; ++trQ) {
    const int q = trQ * 16 + l15;
    vu2 cinN[4];
    if (trQ < 3) {
#pragma unroll
      for (int tcK = 0; tcK < 4; ++tcK)
        cinN[tcK] = *(const vu2*)(bpb + (q + 16) * 64 + tcK * 16 + g * 4);
    }
    const vh8 q8A = cat8(qBA[0][trQ], qBA[1][trQ]);
    const vh8 q8B = cat8(qBB[0][trQ], qBB[1][trQ]);
    vf4 sA[4], sB[4];
#pragma unroll
    for (int tcK = 0; tcK < 4; ++tcK) {
      vf4 cin = unpack_bf4(cinC[tcK]);  // shared A/B
      sA[tcK] = __builtin_amdgcn_mfma_f32_16x16x32_f16(cat8(kAA[0][tcK], kAA[1][tcK]), q8A, cin, 0, 0, 0);
      sB[tcK] = __builtin_amdgcn_mfma_f32_16x16x32_f16(cat8(kAB[0][tcK], kAB[1][tcK]), q8B, cin, 0, 0, 0);
    }
    float sumA = 0.f, sumB = 0.f;
#pragma unroll
    for (int tcK = 0; tcK < 4; ++tcK)
#pragma unroll
      for (int r = 0; r < 4; ++r) {
        float eA = __expf(sA[tcK][r]); sA[tcK][r] = eA; sumA += eA;
        float eB = __expf(sB[tcK][r]); sB[tcK][r] = eB; sumB += eB;
      }
    sumA += __shfl_xor(sumA, 16, 64);
    sumB += __shfl_xor(sumB, 16, 64);
    sumA += __shfl_xor(sumA, 32, 64);
    sumB += __shfl_xor(sumB, 32, 64);
    float ivA = 1.0f / sumA, ivB = 1.0f / sumB;
    vh4 pA[4], pB[4];
#pragma unroll
    for (int tcK = 0; tcK < 4; ++tcK) {
      pA[tcK] = pack4h(sA[tcK][0], sA[tcK][1], sA[tcK][2], sA[tcK][3]);
      pB[tcK] = pack4h(sB[tcK][0], sB[tcK][1], sB[tcK][2], sB[tcK][3]);
    }
    vf4 o0A = (vf4){0.f,0.f,0.f,0.f}, o1A = o0A, o0B = o0A, o1B = o0A;
#pragma unroll
    for (int tp = 0; tp < 2; ++tp) {
      const vh8 p8A = cat8(pA[2 * tp], pA[2 * tp + 1]);
      const vh8 p8B = cat8(pB[2 * tp], pB[2 * tp + 1]);
      o0A = __builtin_amdgcn_mfma_f32_16x16x32_f16(cat8(vAA[0][2 * tp], vAA[0][2 * tp + 1]), p8A, o0A, 0, 0, 0);
      o0B = __builtin_amdgcn_mfma_f32_16x16x32_f16(cat8(vAB[0][2 * tp], vAB[0][2 * tp + 1]), p8B, o0B, 0, 0, 0);
      o1A = __builtin_amdgcn_mfma_f32_16x16x32_f16(cat8(vAA[1][2 * tp], vAA[1][2 * tp + 1]), p8A, o1A, 0, 0, 0);
      o1B = __builtin_amdgcn_mfma_f32_16x16x32_f16(cat8(vAB[1][2 * tp], vAB[1][2 * tp + 1]), p8B, o1B, 0, 0, 0);
    }
    {
      int db0 = (w * 32 + g * 4) * 2;
      int db1 = (w * 32 + 16 + g * 4) * 2;
      int o0 = q * 256 + (db0 ^ ((q & 7) << 4));
      int o1 = q * 256 + (db1 ^ ((q & 7) << 4));
      vu2 p;
      p[0] = cvtpk(o0A[0] * ivA, o0A[1] * ivA); p[1] = cvtpk(o0A[2] * ivA, o0A[3] * ivA);
      *(vu2*)(ldsA + o0) = p;
      p[0] = cvtpk(o1A[0] * ivA, o1A[1] * ivA); p[1] = cvtpk(o1A[2] * ivA, o1A[3] * ivA);
      *(vu2*)(ldsA + o1) = p;
      p[0] = cvtpk(o0B[0] * ivB, o0B[1] * ivB); p[1] = cvtpk(o0B[2] * ivB, o0B[3] * ivB);
      *(vu2*)(ldsB + o0) = p;
      p[0] = cvtpk(o1B[0] * ivB, o1B[1] * ivB); p[1] = cvtpk(o1B[2] * ivB, o1B[3] * ivB);
      *(vu2*)(ldsB + o1) = p;
    }
#pragma unroll
    for (int tcK = 0; tcK < 4; ++tcK) cinC[tcK] = cinN[tcK];
  }

  // ---- GEMM2 weights/bias loaded BEFORE the barrier (latency hides under it) ----
  vs8 bw2[2][4];
  vf4 pb2[2];
#pragma unroll
  for (int ci = 0; ci < 2; ++ci) {
    int ct = w + ci * 4;
    const short* wr = proj_wb + (ct * 16 + l15) * DIMC;
#pragma unroll
    for (int kk = 0; kk < 4; ++kk) bw2[ci][kk] = *(const vs8*)(wr + kk * 32 + g * 8);
    pb2[ci] = *(const vf4*)(proj_b + ct * 16 + g * 4);
  }
  __syncthreads();

  // ---- GEMM2 (swapped) for both windows; weights shared ----
  float* outA = out + (size_t)winA * (NTOK * DIMC);
  float* outB = outA + NTOK * DIMC;
#pragma unroll
  for (int ci = 0; ci < 2; ++ci) {
    int ct = w + ci * 4;
    NO_CSE();
    vf4 accA[4], accB[4];
#pragma unroll
    for (int tr = 0; tr < 4; ++tr) { accA[tr] = pb2[ci]; accB[tr] = pb2[ci]; }
#pragma unroll
    for (int kk = 0; kk < 4; ++kk)
#pragma unroll
      for (int tr = 0; tr < 4; ++tr) {
        int row = tr * 16 + l15;
        int off = row * 256 + ((kk * 64 + g * 16) ^ ((row & 7) << 4));
        accA[tr] = __builtin_amdgcn_mfma_f32_16x16x32_bf16(bw2[ci][kk], *(const vs8*)(ldsA + off), accA[tr], 0, 0, 0);
        accB[tr] = __builtin_amdgcn_mfma_f32_16x16x32_bf16(bw2[ci][kk], *(const vs8*)(ldsB + off), accB[tr], 0, 0, 0);
      }
#pragma unroll
    for (int tr = 0; tr < 4; ++tr) {
      int token = tr * 16 + l15;
      if (token < NTOK) {
        *(vf4*)(outA + token * DIMC + ct * 16 + g * 4) = accA[tr];
        *(vf4*)(outB + token * DIMC + ct * 16 + g * 4) = accB[tr];
      }
    }
  }
}

extern "C" void kernel_launch(void* const* d_in, const int* in_sizes, int n_in,
                              void* d_out, int out_size, void* d_ws, size_t ws_size,
                              hipStream_t stream) {
  const float* x          = (const float*)d_in[0];
  const float* qkv_w      = (const float*)d_in[1];
  const float* qkv_b      = (const float*)d_in[2];
  const float* proj_w     = (const float*)d_in[3];
  const float* proj_b     = (const float*)d_in[4];
  const float* bias_table = (const float*)d_in[5];
  const int*   rel_index  = (const int*)d_in[6];
  float* out = (float*)d_out;

  short* qkv_wb   = (short*)d_ws;                      // 49152 bf16
  short* proj_wb  = (short*)((char*)d_ws + 98304);     // 16384 bf16
  short* bias_bf  = (short*)((char*)d_ws + 131072);    // 4*64*64 bf16 = 32KB

  prep_kernel<<<320, 256, 0, stream>>>(qkv_w, proj_w, bias_table, rel_index,
                                       qkv_wb, proj_wb, bias_bf);
  win_attn<<<NWIN / 2, 256, 0, stream>>>(x, qkv_b, proj_b, qkv_wb, proj_wb, bias_bf, out);
}

// Round 16
// 79.836 us; speedup vs baseline: 1.5911x; 1.0155x over previous
//
#include <hip/hip_runtime.h>

#define NWIN 4096
#define NTOK 49
#define DIMC 128
#define QK_SCALE 0.17677669529663689f  // 32^-0.5

typedef __attribute__((ext_vector_type(8))) short vs8;        // 8 bf16 (4 VGPRs)
typedef __attribute__((ext_vector_type(4))) float vf4;
typedef __attribute__((ext_vector_type(2))) unsigned vu2;     // 2 packed bf16x2
typedef __attribute__((ext_vector_type(4))) _Float16 vh4;     // 4 f16 (2 VGPRs)
typedef __attribute__((ext_vector_type(8))) _Float16 vh8;     // 8 f16 (4 VGPRs) — K=32 MFMA operand
typedef __attribute__((ext_vector_type(2))) __fp16 vp2;       // cvt_pkrtz result type

#define NO_CSE() asm volatile("" ::: "memory")
// 4-bit row swizzle: 16 distinct 16B slots per 256B row (was 3-bit/8 slots ->
// 8-way bank conflict on 64-lane b128 frag reads; 4-bit -> 4-way. m136: 8-way
// costs 2.94x, 4-way 1.58x). Bijective: (row&15)<<4 <= 240 < 256.
#define SWZ(row) (((row) & 15) << 4)

__device__ __forceinline__ unsigned cvtpk(float a, float b) {  // 2xf32 -> packed bf16x2
  unsigned r;
  asm("v_cvt_pk_bf16_f32 %0, %1, %2" : "=v"(r) : "v"(a), "v"(b));
  return r;
}

__device__ __forceinline__ vh4 pack4h(float a0, float a1, float a2, float a3) {
  union { vh4 v; vp2 h[2]; } u;
  u.h[0] = __builtin_amdgcn_cvt_pkrtz(a0, a1);
  u.h[1] = __builtin_amdgcn_cvt_pkrtz(a2, a3);
  return u.v;
}

__device__ __forceinline__ vh8 cat8(vh4 a, vh4 b) {
  union { vh8 v8; vh4 v4[2]; } u;
  u.v4[0] = a; u.v4[1] = b;
  return u.v8;
}

__device__ __forceinline__ vf4 unpack_bf4(vu2 b) {  // 4 packed bf16 -> vf4
  union { unsigned u; float f; } a0, a1, a2, a3;
  a0.u = b[0] << 16; a1.u = b[0] & 0xffff0000u;
  a2.u = b[1] << 16; a3.u = b[1] & 0xffff0000u;
  return (vf4){a0.f, a1.f, a2.f, a3.f};
}

__device__ __forceinline__ short f2bf(float f) {
  union { float f; unsigned u; } x; x.f = f;
  unsigned r = x.u + 0x7fffu + ((x.u >> 16) & 1u);
  return (short)(r >> 16);
}

// ---------------- prep: weights->bf16, bias table -> padded bf16 [4][64][64] ----------------
__global__ void prep_kernel(const float* __restrict__ qkv_w, const float* __restrict__ proj_w,
                            const float* __restrict__ bias_table, const int* __restrict__ rel_index,
                            short* __restrict__ qkv_wb, short* __restrict__ proj_wb,
                            short* __restrict__ bias_bf) {
  int i = blockIdx.x * 256 + threadIdx.x;
  if (i < 49152) qkv_wb[i] = f2bf(qkv_w[i]);
  int j = i - 49152;
  if (j >= 0 && j < 16384) proj_wb[j] = f2bf(proj_w[j]);
  int k = i - 65536;
  if (k >= 0 && k < 16384) {
    int h = k >> 12, rc = k & 4095, r = rc >> 6, c = rc & 63;
    float v = -1e30f;
    if (r < NTOK && c < NTOK) v = bias_table[rel_index[r * NTOK + c] * 4 + h];
    bias_bf[k] = f2bf(v);
  }
}

// ---------------- fused window attention — TWO windows per block, pipelined ----------------
// block = 2 windows (A,B), 4 waves; wave w owns head w of BOTH windows (2x ILP).
// R16: (1) 4-bit LDS swizzle (8-way -> 4-way bank conflicts on frag reads,
// ~free O-writes); (2) s_setprio(1) around MFMA clusters (waves run
// phase-independent -> T5 regime). Retained: GEMM1 6-tile weight-prefetch
// pipeline, cin prefetch, GEMM2 pre-barrier weight loads, no-max softmax,
// per-head normalization at O-write, bias as C-in, K=32 f16 attention MFMAs,
// LDS frag re-reads w/ NO_CSE. LDS 32KB = 2 x 16KB halves. 3 barriers.
__launch_bounds__(256)
__global__ void win_attn(const float* __restrict__ x,
                         const float* __restrict__ qkv_b,
                         const float* __restrict__ proj_b,
                         const short* __restrict__ qkv_wb,
                         const short* __restrict__ proj_wb,
                         const short* __restrict__ bias_bf,
                         float* __restrict__ out) {
  __shared__ __align__(16) char lds[32768];
  char* const ldsA = lds;
  char* const ldsB = lds + 16384;

  const int tid  = threadIdx.x;
  const int lane = tid & 63;
  const int w    = tid >> 6;
  const int l15  = lane & 15;
  const int g    = lane >> 4;
  const int winA = blockIdx.x * 2;

  // ---- stage both windows: issue all loads, then cvt+write ----
  const float* xwA = x + (size_t)winA * (NTOK * DIMC);
  const float* xwB = xwA + NTOK * DIMC;
  vf4 aA[4], bA[4], aB[4], bB[4];
  int srow[4], sc16[4];
#pragma unroll
  for (int it = 0; it < 4; ++it) {
    int chunk = tid + it * 256;
    srow[it] = chunk >> 4; sc16[it] = chunk & 15;
    if (srow[it] < NTOK) {
      const float* sA = xwA + srow[it] * DIMC + sc16[it] * 8;
      const float* sB = xwB + srow[it] * DIMC + sc16[it] * 8;
      aA[it] = *(const vf4*)sA; bA[it] = *(const vf4*)(sA + 4);
      aB[it] = *(const vf4*)sB; bB[it] = *(const vf4*)(sB + 4);
    }
  }
#pragma unroll
  for (int it = 0; it < 4; ++it) {
    union { vs8 s; unsigned u[4]; } pA, pB;
    if (srow[it] < NTOK) {
      pA.u[0] = cvtpk(aA[it].x, aA[it].y); pA.u[1] = cvtpk(aA[it].z, aA[it].w);
      pA.u[2] = cvtpk(bA[it].x, bA[it].y); pA.u[3] = cvtpk(bA[it].z, bA[it].w);
      pB.u[0] = cvtpk(aB[it].x, aB[it].y); pB.u[1] = cvtpk(aB[it].z, aB[it].w);
      pB.u[2] = cvtpk(bB[it].x, bB[it].y); pB.u[3] = cvtpk(bB[it].z, bB[it].w);
    } else {
      pA.u[0] = pA.u[1] = pA.u[2] = pA.u[3] = 0u;
      pB.u[0] = pB.u[1] = pB.u[2] = pB.u[3] = 0u;
    }
    int off = srow[it] * 256 + ((sc16[it] * 16) ^ SWZ(srow[it]));
    *(vs8*)(ldsA + off) = pA.s;
    *(vs8*)(ldsB + off) = pB.s;
  }
  __syncthreads();

  // ---- GEMM1: flat 6-tile pipeline. tile j: kind=j%3 (0=Q,1=K,2=V), dt=j/3,
  //      c = 8*kind + 2*w + dt. Next tile's weights prefetched before the fence.
  vh4 qBA[2][4], qBB[2][4], kAA[2][4], kAB[2][4], vAA[2][4], vAB[2][4];
  vs8 bwC[4];
  vf4 qbC = (vf4){0.f, 0.f, 0.f, 0.f};
  float bvC = 0.f;
  {
    const int c0 = 2 * w;  // j=0: Q, dt=0
    const short* wr = qkv_wb + (c0 * 16 + l15) * DIMC;
#pragma unroll
    for (int kk = 0; kk < 4; ++kk) bwC[kk] = *(const vs8*)(wr + kk * 32 + g * 8);
    qbC = *(const vf4*)(qkv_b + c0 * 16 + g * 4);
  }
#pragma unroll
  for (int j = 0; j < 6; ++j) {
    const int kind = j % 3, dt = j / 3;
    // prefetch next tile's weights+bias BEFORE this tile's fence
    vs8 bwN[4];
    vf4 qbN = (vf4){0.f, 0.f, 0.f, 0.f};
    float bvN = 0.f;
    if (j < 5) {
      const int kn = (j + 1) % 3, dn = (j + 1) / 3;
      const int cn = 8 * kn + 2 * w + dn;
      const short* wr = qkv_wb + (cn * 16 + l15) * DIMC;
#pragma unroll
      for (int kk = 0; kk < 4; ++kk) bwN[kk] = *(const vs8*)(wr + kk * 32 + g * 8);
      if (kn == 2) bvN = qkv_b[cn * 16 + l15];
      else         qbN = *(const vf4*)(qkv_b + cn * 16 + g * 4);
    }
    NO_CSE();
    vf4 accA[4], accB[4];
#pragma unroll
    for (int tr = 0; tr < 4; ++tr) {
      accA[tr] = (kind == 2) ? (vf4){bvC, bvC, bvC, bvC} : qbC;
      accB[tr] = accA[tr];
    }
    __builtin_amdgcn_s_setprio(1);
#pragma unroll
    for (int kk = 0; kk < 4; ++kk)
#pragma unroll
      for (int tr = 0; tr < 4; ++tr) {
        int row = tr * 16 + l15;
        int off = row * 256 + ((kk * 64 + g * 16) ^ SWZ(row));
        vs8 fA = *(const vs8*)(ldsA + off);
        vs8 fB = *(const vs8*)(ldsB + off);
        if (kind == 2) {  // V: normal orientation
          accA[tr] = __builtin_amdgcn_mfma_f32_16x16x32_bf16(fA, bwC[kk], accA[tr], 0, 0, 0);
          accB[tr] = __builtin_amdgcn_mfma_f32_16x16x32_bf16(fB, bwC[kk], accB[tr], 0, 0, 0);
        } else {          // Q/K: swapped
          accA[tr] = __builtin_amdgcn_mfma_f32_16x16x32_bf16(bwC[kk], fA, accA[tr], 0, 0, 0);
          accB[tr] = __builtin_amdgcn_mfma_f32_16x16x32_bf16(bwC[kk], fB, accB[tr], 0, 0, 0);
        }
      }
    __builtin_amdgcn_s_setprio(0);
#pragma unroll
    for (int tr = 0; tr < 4; ++tr) {
      if (kind == 0) {
        qBA[dt][tr] = pack4h(accA[tr][0] * QK_SCALE, accA[tr][1] * QK_SCALE,
                             accA[tr][2] * QK_SCALE, accA[tr][3] * QK_SCALE);
        qBB[dt][tr] = pack4h(accB[tr][0] * QK_SCALE, accB[tr][1] * QK_SCALE,
                             accB[tr][2] * QK_SCALE, accB[tr][3] * QK_SCALE);
      } else if (kind == 1) {
        kAA[dt][tr] = pack4h(accA[tr][0], accA[tr][1], accA[tr][2], accA[tr][3]);
        kAB[dt][tr] = pack4h(accB[tr][0], accB[tr][1], accB[tr][2], accB[tr][3]);
      } else {
        vAA[dt][tr] = pack4h(accA[tr][0], accA[tr][1], accA[tr][2], accA[tr][3]);
        vAB[dt][tr] = pack4h(accB[tr][0], accB[tr][1], accB[tr][2], accB[tr][3]);
      }
    }
#pragma unroll
    for (int kk = 0; kk < 4; ++kk) bwC[kk] = bwN[kk];
    qbC = qbN; bvC = bvN;
  }
  __syncthreads();  // X dead in both halves -> reusable for O exchange

  // ---- attention fused per q-row-tile, both windows interleaved; cin prefetched ----
  const short* bpb = bias_bf + w * 4096;
  vu2 cinC[4];
#pragma unroll
  for (int tcK = 0; tcK < 4; ++tcK)
    cinC[tcK] = *(const vu2*)(bpb + (0 * 16 + l15) * 64 + tcK * 16 + g * 4);
#pragma unroll
  for (int trQ = 0; trQ < 4; ++trQ) {
    const int q = trQ * 16 + l15;
    vu2 cinN[4];
    if (trQ < 3) {
#pragma unroll
      for (int tcK = 0; tcK < 4; ++tcK)
        cinN[tcK] = *(const vu2*)(bpb + (q + 16) * 64 + tcK * 16 + g * 4);
    }
    const vh8 q8A = cat8(qBA[0][trQ], qBA[1][trQ]);
    const vh8 q8B = cat8(qBB[0][trQ], qBB[1][trQ]);
    vf4 sA[4], sB[4];
    __builtin_amdgcn_s_setprio(1);
#pragma unroll
    for (int tcK = 0; tcK < 4; ++tcK) {
      vf4 cin = unpack_bf4(cinC[tcK]);  // shared A/B
      sA[tcK] = __builtin_amdgcn_mfma_f32_16x16x32_f16(cat8(kAA[0][tcK], kAA[1][tcK]), q8A, cin, 0, 0, 0);
      sB[tcK] = __builtin_amdgcn_mfma_f32_16x16x32_f16(cat8(kAB[0][tcK], kAB[1][tcK]), q8B, cin, 0, 0, 0);
    }
    __builtin_amdgcn_s_setprio(0);
    float sumA = 0.f, sumB = 0.f;
#pragma unroll
    for (int tcK = 0; tcK < 4; ++tcK)
#pragma unroll
      for (int r = 0; r < 4; ++r) {
        float eA = __expf(sA[tcK][r]); sA[tcK][r] = eA; sumA += eA;
        float eB = __expf(sB[tcK][r]); sB[tcK][r] = eB; sumB += eB;
      }
    sumA += __shfl_xor(sumA, 16, 64);
    sumB += __shfl_xor(sumB, 16, 64);
    sumA += __shfl_xor(sumA, 32, 64);
    sumB += __shfl_xor(sumB, 32, 64);
    float ivA = 1.0f / sumA, ivB = 1.0f / sumB;
    vh4 pA[4], pB[4];
#pragma unroll
    for (int tcK = 0; tcK < 4; ++tcK) {
      pA[tcK] = pack4h(sA[tcK][0], sA[tcK][1], sA[tcK][2], sA[tcK][3]);
      pB[tcK] = pack4h(sB[tcK][0], sB[tcK][1], sB[tcK][2], sB[tcK][3]);
    }
    vf4 o0A = (vf4){0.f,0.f,0.f,0.f}, o1A = o0A, o0B = o0A, o1B = o0A;
    __builtin_amdgcn_s_setprio(1);
#pragma unroll
    for (int tp = 0; tp < 2; ++tp) {
      const vh8 p8A = cat8(pA[2 * tp], pA[2 * tp + 1]);
      const vh8 p8B = cat8(pB[2 * tp], pB[2 * tp + 1]);
      o0A = __builtin_amdgcn_mfma_f32_16x16x32_f16(cat8(vAA[0][2 * tp], vAA[0][2 * tp + 1]), p8A, o0A, 0, 0, 0);
      o0B = __builtin_amdgcn_mfma_f32_16x16x32_f16(cat8(vAB[0][2 * tp], vAB[0][2 * tp + 1]), p8B, o0B, 0, 0, 0);
      o1A = __builtin_amdgcn_mfma_f32_16x16x32_f16(cat8(vAA[1][2 * tp], vAA[1][2 * tp + 1]), p8A, o1A, 0, 0, 0);
      o1B = __builtin_amdgcn_mfma_f32_16x16x32_f16(cat8(vAB[1][2 * tp], vAB[1][2 * tp + 1]), p8B, o1B, 0, 0, 0);
    }
    __builtin_amdgcn_s_setprio(0);
    {
      int db0 = (w * 32 + g * 4) * 2;
      int db1 = (w * 32 + 16 + g * 4) * 2;
      int o0 = q * 256 + (db0 ^ SWZ(q));
      int o1 = q * 256 + (db1 ^ SWZ(q));
      vu2 p;
      p[0] = cvtpk(o0A[0] * ivA, o0A[1] * ivA); p[1] = cvtpk(o0A[2] * ivA, o0A[3] * ivA);
      *(vu2*)(ldsA + o0) = p;
      p[0] = cvtpk(o1A[0] * ivA, o1A[1] * ivA); p[1] = cvtpk(o1A[2] * ivA, o1A[3] * ivA);
      *(vu2*)(ldsA + o1) = p;
      p[0] = cvtpk(o0B[0] * ivB, o0B[1] * ivB); p[1] = cvtpk(o0B[2] * ivB, o0B[3] * ivB);
      *(vu2*)(ldsB + o0) = p;
      p[0] = cvtpk(o1B[0] * ivB, o1B[1] * ivB); p[1] = cvtpk(o1B[2] * ivB, o1B[3] * ivB);
      *(vu2*)(ldsB + o1) = p;
    }
#pragma unroll
    for (int tcK = 0; tcK < 4; ++tcK) cinC[tcK] = cinN[tcK];
  }

  // ---- GEMM2 weights/bias loaded BEFORE the barrier (latency hides under it) ----
  vs8 bw2[2][4];
  vf4 pb2[2];
#pragma unroll
  for (int ci = 0; ci < 2; ++ci) {
    int ct = w + ci * 4;
    const short* wr = proj_wb + (ct * 16 + l15) * DIMC;
#pragma unroll
    for (int kk = 0; kk < 4; ++kk) bw2[ci][kk] = *(const vs8*)(wr + kk * 32 + g * 8);
    pb2[ci] = *(const vf4*)(proj_b + ct * 16 + g * 4);
  }
  __syncthreads();

  // ---- GEMM2 (swapped) for both windows; weights shared ----
  float* outA = out + (size_t)winA * (NTOK * DIMC);
  float* outB = outA + NTOK * DIMC;
#pragma unroll
  for (int ci = 0; ci < 2; ++ci) {
    int ct = w + ci * 4;
    NO_CSE();
    vf4 accA[4], accB[4];
#pragma unroll
    for (int tr = 0; tr < 4; ++tr) { accA[tr] = pb2[ci]; accB[tr] = pb2[ci]; }
    __builtin_amdgcn_s_setprio(1);
#pragma unroll
    for (int kk = 0; kk < 4; ++kk)
#pragma unroll
      for (int tr = 0; tr < 4; ++tr) {
        int row = tr * 16 + l15;
        int off = row * 256 + ((kk * 64 + g * 16) ^ SWZ(row));
        accA[tr] = __builtin_amdgcn_mfma_f32_16x16x32_bf16(bw2[ci][kk], *(const vs8*)(ldsA + off), accA[tr], 0, 0, 0);
        accB[tr] = __builtin_amdgcn_mfma_f32_16x16x32_bf16(bw2[ci][kk], *(const vs8*)(ldsB + off), accB[tr], 0, 0, 0);
      }
    __builtin_amdgcn_s_setprio(0);
#pragma unroll
    for (int tr = 0; tr < 4; ++tr) {
      int token = tr * 16 + l15;
      if (token < NTOK) {
        *(vf4*)(outA + token * DIMC + ct * 16 + g * 4) = accA[tr];
        *(vf4*)(outB + token * DIMC + ct * 16 + g * 4) = accB[tr];
      }
    }
  }
}

extern "C" void kernel_launch(void* const* d_in, const int* in_sizes, int n_in,
                              void* d_out, int out_size, void* d_ws, size_t ws_size,
                              hipStream_t stream) {
  const float* x          = (const float*)d_in[0];
  const float* qkv_w      = (const float*)d_in[1];
  const float* qkv_b      = (const float*)d_in[2];
  const float* proj_w     = (const float*)d_in[3];
  const float* proj_b     = (const float*)d_in[4];
  const float* bias_table = (const float*)d_in[5];
  const int*   rel_index  = (const int*)d_in[6];
  float* out = (float*)d_out;

  short* qkv_wb   = (short*)d_ws;                      // 49152 bf16
  short* proj_wb  = (short*)((char*)d_ws + 98304);     // 16384 bf16
  short* bias_bf  = (short*)((char*)d_ws + 131072);    // 4*64*64 bf16 = 32KB

  prep_kernel<<<320, 256, 0, stream>>>(qkv_w, proj_w, bias_table, rel_index,
                                       qkv_wb, proj_wb, bias_bf);
  win_attn<<<NWIN / 2, 256, 0, stream>>>(x, qkv_b, proj_b, qkv_wb, proj_wb, bias_bf, out);
}

// Round 17
// 78.588 us; speedup vs baseline: 1.6163x; 1.0159x over previous
//
#include <hip/hip_runtime.h>

#define NWIN 4096
#define NTOK 49
#define DIMC 128
#define QK_SCALE 0.17677669529663689f   // 32^-0.5
#define LOG2E 1.4426950408889634f

typedef __attribute__((ext_vector_type(8))) short vs8;        // 8 bf16 (4 VGPRs)
typedef __attribute__((ext_vector_type(4))) float vf4;
typedef __attribute__((ext_vector_type(2))) unsigned vu2;     // 2 packed bf16x2
typedef __attribute__((ext_vector_type(4))) _Float16 vh4;     // 4 f16 (2 VGPRs)
typedef __attribute__((ext_vector_type(8))) _Float16 vh8;     // 8 f16 (4 VGPRs) — K=32 MFMA operand
typedef __attribute__((ext_vector_type(2))) __fp16 vp2;       // cvt_pkrtz result type

#define NO_CSE() asm volatile("" ::: "memory")
// 4-bit row swizzle: 16 distinct 16B slots per 256B row (R16: 8-way -> 4-way
// bank conflict; SQ_LDS_BANK_CONFLICT 8.9M -> 0.52M).
#define SWZ(row) (((row) & 15) << 4)

__device__ __forceinline__ unsigned cvtpk(float a, float b) {  // 2xf32 -> packed bf16x2
  unsigned r;
  asm("v_cvt_pk_bf16_f32 %0, %1, %2" : "=v"(r) : "v"(a), "v"(b));
  return r;
}

__device__ __forceinline__ float exp2f_raw(float x) {  // 2^x, no log2e mul
  float r;
  asm("v_exp_f32 %0, %1" : "=v"(r) : "v"(x));
  return r;
}

__device__ __forceinline__ vh4 pack4h(float a0, float a1, float a2, float a3) {
  union { vh4 v; vp2 h[2]; } u;
  u.h[0] = __builtin_amdgcn_cvt_pkrtz(a0, a1);
  u.h[1] = __builtin_amdgcn_cvt_pkrtz(a2, a3);
  return u.v;
}

__device__ __forceinline__ vh8 cat8(vh4 a, vh4 b) {
  union { vh8 v8; vh4 v4[2]; } u;
  u.v4[0] = a; u.v4[1] = b;
  return u.v8;
}

__device__ __forceinline__ vf4 unpack_bf4(vu2 b) {  // 4 packed bf16 -> vf4
  union { unsigned u; float f; } a0, a1, a2, a3;
  a0.u = b[0] << 16; a1.u = b[0] & 0xffff0000u;
  a2.u = b[1] << 16; a3.u = b[1] & 0xffff0000u;
  return (vf4){a0.f, a1.f, a2.f, a3.f};
}

__device__ __forceinline__ short f2bf(float f) {
  union { float f; unsigned u; } x; x.f = f;
  unsigned r = x.u + 0x7fffu + ((x.u >> 16) & 1u);
  return (short)(r >> 16);
}

// ---------------- prep: weights->bf16, bias*log2e -> padded bf16 [4][64][64] ----------------
__global__ void prep_kernel(const float* __restrict__ qkv_w, const float* __restrict__ proj_w,
                            const float* __restrict__ bias_table, const int* __restrict__ rel_index,
                            short* __restrict__ qkv_wb, short* __restrict__ proj_wb,
                            short* __restrict__ bias_bf) {
  int i = blockIdx.x * 256 + threadIdx.x;
  if (i < 49152) qkv_wb[i] = f2bf(qkv_w[i]);
  int j = i - 49152;
  if (j >= 0 && j < 16384) proj_wb[j] = f2bf(proj_w[j]);
  int k = i - 65536;
  if (k >= 0 && k < 16384) {
    int h = k >> 12, rc = k & 4095, r = rc >> 6, c = rc & 63;
    float v = -1e30f;
    if (r < NTOK && c < NTOK) v = bias_table[rel_index[r * NTOK + c] * 4 + h];
    bias_bf[k] = f2bf(v * LOG2E);   // fold log2e: softmax uses 2^x directly
  }
}

// ---------------- fused window attention — TWO windows per block, pipelined ----------------
// block = 2 windows (A,B), 4 waves; wave w owns head w of BOTH windows (2x ILP).
// R17: (1) exp2 path — log2e folded into Q pack-scale + bias table; raw
// v_exp_f32 (removes 256 v_mul/wave on softmax path); (2) j=0 GEMM1 weights
// and trQ=0 attention bias loads hoisted ABOVE their barriers (compiler can't
// hoist loads across __syncthreads; latency now hides under staging/barrier).
// Retained: 4-bit LDS swizzle, setprio around MFMA clusters, GEMM1 6-tile
// weight-prefetch pipeline, cin prefetch, GEMM2 pre-barrier weight loads,
// no-max softmax, per-head normalization at O-write, bias as C-in, K=32 f16
// attention MFMAs, LDS frag re-reads w/ NO_CSE. LDS 32KB. 3 barriers.
__launch_bounds__(256)
__global__ void win_attn(const float* __restrict__ x,
                         const float* __restrict__ qkv_b,
                         const float* __restrict__ proj_b,
                         const short* __restrict__ qkv_wb,
                         const short* __restrict__ proj_wb,
                         const short* __restrict__ bias_bf,
                         float* __restrict__ out) {
  __shared__ __align__(16) char lds[32768];
  char* const ldsA = lds;
  char* const ldsB = lds + 16384;

  const int tid  = threadIdx.x;
  const int lane = tid & 63;
  const int w    = tid >> 6;
  const int l15  = lane & 15;
  const int g    = lane >> 4;
  const int winA = blockIdx.x * 2;

  // ---- stage both windows: issue all loads first ----
  const float* xwA = x + (size_t)winA * (NTOK * DIMC);
  const float* xwB = xwA + NTOK * DIMC;
  vf4 aA[4], bA[4], aB[4], bB[4];
  int srow[4], sc16[4];
#pragma unroll
  for (int it = 0; it < 4; ++it) {
    int chunk = tid + it * 256;
    srow[it] = chunk >> 4; sc16[it] = chunk & 15;
    if (srow[it] < NTOK) {
      const float* sA = xwA + srow[it] * DIMC + sc16[it] * 8;
      const float* sB = xwB + srow[it] * DIMC + sc16[it] * 8;
      aA[it] = *(const vf4*)sA; bA[it] = *(const vf4*)(sA + 4);
      aB[it] = *(const vf4*)sB; bB[it] = *(const vf4*)(sB + 4);
    }
  }

  // ---- j=0 GEMM1 weights+bias issued HERE: latency hides under staging ----
  vs8 bwC[4];
  vf4 qbC;
  float bvC = 0.f;
  {
    const int c0 = 2 * w;  // j=0: Q, dt=0
    const short* wr = qkv_wb + (c0 * 16 + l15) * DIMC;
#pragma unroll
    for (int kk = 0; kk < 4; ++kk) bwC[kk] = *(const vs8*)(wr + kk * 32 + g * 8);
    qbC = *(const vf4*)(qkv_b + c0 * 16 + g * 4);
  }

  // ---- convert + write staging ----
#pragma unroll
  for (int it = 0; it < 4; ++it) {
    union { vs8 s; unsigned u[4]; } pA, pB;
    if (srow[it] < NTOK) {
      pA.u[0] = cvtpk(aA[it].x, aA[it].y); pA.u[1] = cvtpk(aA[it].z, aA[it].w);
      pA.u[2] = cvtpk(bA[it].x, bA[it].y); pA.u[3] = cvtpk(bA[it].z, bA[it].w);
      pB.u[0] = cvtpk(aB[it].x, aB[it].y); pB.u[1] = cvtpk(aB[it].z, aB[it].w);
      pB.u[2] = cvtpk(bB[it].x, bB[it].y); pB.u[3] = cvtpk(bB[it].z, bB[it].w);
    } else {
      pA.u[0] = pA.u[1] = pA.u[2] = pA.u[3] = 0u;
      pB.u[0] = pB.u[1] = pB.u[2] = pB.u[3] = 0u;
    }
    int off = srow[it] * 256 + ((sc16[it] * 16) ^ SWZ(srow[it]));
    *(vs8*)(ldsA + off) = pA.s;
    *(vs8*)(ldsB + off) = pB.s;
  }
  __syncthreads();

  // ---- GEMM1: flat 6-tile pipeline. tile j: kind=j%3 (0=Q,1=K,2=V), dt=j/3,
  //      c = 8*kind + 2*w + dt. Next tile's weights prefetched before the fence.
  vh4 qBA[2][4], qBB[2][4], kAA[2][4], kAB[2][4], vAA[2][4], vAB[2][4];
  const float QSC2 = QK_SCALE * LOG2E;  // fold log2e into Q
#pragma unroll
  for (int j = 0; j < 6; ++j) {
    const int kind = j % 3, dt = j / 3;
    vs8 bwN[4];
    vf4 qbN = (vf4){0.f, 0.f, 0.f, 0.f};
    float bvN = 0.f;
    if (j < 5) {
      const int kn = (j + 1) % 3, dn = (j + 1) / 3;
      const int cn = 8 * kn + 2 * w + dn;
      const short* wr = qkv_wb + (cn * 16 + l15) * DIMC;
#pragma unroll
      for (int kk = 0; kk < 4; ++kk) bwN[kk] = *(const vs8*)(wr + kk * 32 + g * 8);
      if (kn == 2) bvN = qkv_b[cn * 16 + l15];
      else         qbN = *(const vf4*)(qkv_b + cn * 16 + g * 4);
    }
    NO_CSE();
    vf4 accA[4], accB[4];
#pragma unroll
    for (int tr = 0; tr < 4; ++tr) {
      accA[tr] = (kind == 2) ? (vf4){bvC, bvC, bvC, bvC} : qbC;
      accB[tr] = accA[tr];
    }
    __builtin_amdgcn_s_setprio(1);
#pragma unroll
    for (int kk = 0; kk < 4; ++kk)
#pragma unroll
      for (int tr = 0; tr < 4; ++tr) {
        int row = tr * 16 + l15;
        int off = row * 256 + ((kk * 64 + g * 16) ^ SWZ(row));
        vs8 fA = *(const vs8*)(ldsA + off);
        vs8 fB = *(const vs8*)(ldsB + off);
        if (kind == 2) {  // V: normal orientation
          accA[tr] = __builtin_amdgcn_mfma_f32_16x16x32_bf16(fA, bwC[kk], accA[tr], 0, 0, 0);
          accB[tr] = __builtin_amdgcn_mfma_f32_16x16x32_bf16(fB, bwC[kk], accB[tr], 0, 0, 0);
        } else {          // Q/K: swapped
          accA[tr] = __builtin_amdgcn_mfma_f32_16x16x32_bf16(bwC[kk], fA, accA[tr], 0, 0, 0);
          accB[tr] = __builtin_amdgcn_mfma_f32_16x16x32_bf16(bwC[kk], fB, accB[tr], 0, 0, 0);
        }
      }
    __builtin_amdgcn_s_setprio(0);
#pragma unroll
    for (int tr = 0; tr < 4; ++tr) {
      if (kind == 0) {
        qBA[dt][tr] = pack4h(accA[tr][0] * QSC2, accA[tr][1] * QSC2,
                             accA[tr][2] * QSC2, accA[tr][3] * QSC2);
        qBB[dt][tr] = pack4h(accB[tr][0] * QSC2, accB[tr][1] * QSC2,
                             accB[tr][2] * QSC2, accB[tr][3] * QSC2);
      } else if (kind == 1) {
        kAA[dt][tr] = pack4h(accA[tr][0], accA[tr][1], accA[tr][2], accA[tr][3]);
        kAB[dt][tr] = pack4h(accB[tr][0], accB[tr][1], accB[tr][2], accB[tr][3]);
      } else {
        vAA[dt][tr] = pack4h(accA[tr][0], accA[tr][1], accA[tr][2], accA[tr][3]);
        vAB[dt][tr] = pack4h(accB[tr][0], accB[tr][1], accB[tr][2], accB[tr][3]);
      }
    }
#pragma unroll
    for (int kk = 0; kk < 4; ++kk) bwC[kk] = bwN[kk];
    qbC = qbN; bvC = bvN;
  }

  // ---- trQ=0 attention bias issued BEFORE the barrier (latency hides under it) ----
  const short* bpb = bias_bf + w * 4096;
  vu2 cinC[4];
#pragma unroll
  for (int tcK = 0; tcK < 4; ++tcK)
    cinC[tcK] = *(const vu2*)(bpb + l15 * 64 + tcK * 16 + g * 4);
  __syncthreads();  // X dead in both halves -> reusable for O exchange

  // ---- attention fused per q-row-tile, both windows interleaved; cin prefetched ----
#pragma unroll
  for (int trQ = 0; trQ < 4; ++trQ) {
    const int q = trQ * 16 + l15;
    vu2 cinN[4];
    if (trQ < 3) {
#pragma unroll
      for (int tcK = 0; tcK < 4; ++tcK)
        cinN[tcK] = *(const vu2*)(bpb + (q + 16) * 64 + tcK * 16 + g * 4);
    }
    const vh8 q8A = cat8(qBA[0][trQ], qBA[1][trQ]);
    const vh8 q8B = cat8(qBB[0][trQ], qBB[1][trQ]);
    vf4 sA[4], sB[4];
    __builtin_amdgcn_s_setprio(1);
#pragma unroll
    for (int tcK = 0; tcK < 4; ++tcK) {
      vf4 cin = unpack_bf4(cinC[tcK]);  // shared A/B (already *log2e)
      sA[tcK] = __builtin_amdgcn_mfma_f32_16x16x32_f16(cat8(kAA[0][tcK], kAA[1][tcK]), q8A, cin, 0, 0, 0);
      sB[tcK] = __builtin_amdgcn_mfma_f32_16x16x32_f16(cat8(kAB[0][tcK], kAB[1][tcK]), q8B, cin, 0, 0, 0);
    }
    __builtin_amdgcn_s_setprio(0);
    float sumA = 0.f, sumB = 0.f;
#pragma unroll
    for (int tcK = 0; tcK < 4; ++tcK)
#pragma unroll
      for (int r = 0; r < 4; ++r) {
        float eA = exp2f_raw(sA[tcK][r]); sA[tcK][r] = eA; sumA += eA;
        float eB = exp2f_raw(sB[tcK][r]); sB[tcK][r] = eB; sumB += eB;
      }
    sumA += __shfl_xor(sumA, 16, 64);
    sumB += __shfl_xor(sumB, 16, 64);
    sumA += __shfl_xor(sumA, 32, 64);
    sumB += __shfl_xor(sumB, 32, 64);
    float ivA = 1.0f / sumA, ivB = 1.0f / sumB;
    vh4 pA[4], pB[4];
#pragma unroll
    for (int tcK = 0; tcK < 4; ++tcK) {
      pA[tcK] = pack4h(sA[tcK][0], sA[tcK][1], sA[tcK][2], sA[tcK][3]);
      pB[tcK] = pack4h(sB[tcK][0], sB[tcK][1], sB[tcK][2], sB[tcK][3]);
    }
    vf4 o0A = (vf4){0.f,0.f,0.f,0.f}, o1A = o0A, o0B = o0A, o1B = o0A;
    __builtin_amdgcn_s_setprio(1);
#pragma unroll
    for (int tp = 0; tp < 2; ++tp) {
      const vh8 p8A = cat8(pA[2 * tp], pA[2 * tp + 1]);
      const vh8 p8B = cat8(pB[2 * tp], pB[2 * tp + 1]);
      o0A = __builtin_amdgcn_mfma_f32_16x16x32_f16(cat8(vAA[0][2 * tp], vAA[0][2 * tp + 1]), p8A, o0A, 0, 0, 0);
      o0B = __builtin_amdgcn_mfma_f32_16x16x32_f16(cat8(vAB[0][2 * tp], vAB[0][2 * tp + 1]), p8B, o0B, 0, 0, 0);
      o1A = __builtin_amdgcn_mfma_f32_16x16x32_f16(cat8(vAA[1][2 * tp], vAA[1][2 * tp + 1]), p8A, o1A, 0, 0, 0);
      o1B = __builtin_amdgcn_mfma_f32_16x16x32_f16(cat8(vAB[1][2 * tp], vAB[1][2 * tp + 1]), p8B, o1B, 0, 0, 0);
    }
    __builtin_amdgcn_s_setprio(0);
    {
      int db0 = (w * 32 + g * 4) * 2;
      int db1 = (w * 32 + 16 + g * 4) * 2;
      int o0 = q * 256 + (db0 ^ SWZ(q));
      int o1 = q * 256 + (db1 ^ SWZ(q));
      vu2 p;
      p[0] = cvtpk(o0A[0] * ivA, o0A[1] * ivA); p[1] = cvtpk(o0A[2] * ivA, o0A[3] * ivA);
      *(vu2*)(ldsA + o0) = p;
      p[0] = cvtpk(o1A[0] * ivA, o1A[1] * ivA); p[1] = cvtpk(o1A[2] * ivA, o1A[3] * ivA);
      *(vu2*)(ldsA + o1) = p;
      p[0] = cvtpk(o0B[0] * ivB, o0B[1] * ivB); p[1] = cvtpk(o0B[2] * ivB, o0B[3] * ivB);
      *(vu2*)(ldsB + o0) = p;
      p[0] = cvtpk(o1B[0] * ivB, o1B[1] * ivB); p[1] = cvtpk(o1B[2] * ivB, o1B[3] * ivB);
      *(vu2*)(ldsB + o1) = p;
    }
#pragma unroll
    for (int tcK = 0; tcK < 4; ++tcK) cinC[tcK] = cinN[tcK];
  }

  // ---- GEMM2 weights/bias loaded BEFORE the barrier (latency hides under it) ----
  vs8 bw2[2][4];
  vf4 pb2[2];
#pragma unroll
  for (int ci = 0; ci < 2; ++ci) {
    int ct = w + ci * 4;
    const short* wr = proj_wb + (ct * 16 + l15) * DIMC;
#pragma unroll
    for (int kk = 0; kk < 4; ++kk) bw2[ci][kk] = *(const vs8*)(wr + kk * 32 + g * 8);
    pb2[ci] = *(const vf4*)(proj_b + ct * 16 + g * 4);
  }
  __syncthreads();

  // ---- GEMM2 (swapped) for both windows; weights shared ----
  float* outA = out + (size_t)winA * (NTOK * DIMC);
  float* outB = outA + NTOK * DIMC;
#pragma unroll
  for (int ci = 0; ci < 2; ++ci) {
    int ct = w + ci * 4;
    NO_CSE();
    vf4 accA[4], accB[4];
#pragma unroll
    for (int tr = 0; tr < 4; ++tr) { accA[tr] = pb2[ci]; accB[tr] = pb2[ci]; }
    __builtin_amdgcn_s_setprio(1);
#pragma unroll
    for (int kk = 0; kk < 4; ++kk)
#pragma unroll
      for (int tr = 0; tr < 4; ++tr) {
        int row = tr * 16 + l15;
        int off = row * 256 + ((kk * 64 + g * 16) ^ SWZ(row));
        accA[tr] = __builtin_amdgcn_mfma_f32_16x16x32_bf16(bw2[ci][kk], *(const vs8*)(ldsA + off), accA[tr], 0, 0, 0);
        accB[tr] = __builtin_amdgcn_mfma_f32_16x16x32_bf16(bw2[ci][kk], *(const vs8*)(ldsB + off), accB[tr], 0, 0, 0);
      }
    __builtin_amdgcn_s_setprio(0);
#pragma unroll
    for (int tr = 0; tr < 4; ++tr) {
      int token = tr * 16 + l15;
      if (token < NTOK) {
        *(vf4*)(outA + token * DIMC + ct * 16 + g * 4) = accA[tr];
        *(vf4*)(outB + token * DIMC + ct * 16 + g * 4) = accB[tr];
      }
    }
  }
}

extern "C" void kernel_launch(void* const* d_in, const int* in_sizes, int n_in,
                              void* d_out, int out_size, void* d_ws, size_t ws_size,
                              hipStream_t stream) {
  const float* x          = (const float*)d_in[0];
  const float* qkv_w      = (const float*)d_in[1];
  const float* qkv_b      = (const float*)d_in[2];
  const float* proj_w     = (const float*)d_in[3];
  const float* proj_b     = (const float*)d_in[4];
  const float* bias_table = (const float*)d_in[5];
  const int*   rel_index  = (const int*)d_in[6];
  float* out = (float*)d_out;

  short* qkv_wb   = (short*)d_ws;                      // 49152 bf16
  short* proj_wb  = (short*)((char*)d_ws + 98304);     // 16384 bf16
  short* bias_bf  = (short*)((char*)d_ws + 131072);    // 4*64*64 bf16 = 32KB

  prep_kernel<<<320, 256, 0, stream>>>(qkv_w, proj_w, bias_table, rel_index,
                                       qkv_wb, proj_wb, bias_bf);
  win_attn<<<NWIN / 2, 256, 0, stream>>>(x, qkv_b, proj_b, qkv_wb, proj_wb, bias_bf, out);
}